// Round 12
// baseline (642.818 us; speedup 1.0000x reference)
//
#include <hip/hip_runtime.h>
#include <stdint.h>

#define NSITES 256
#define NHID   64
#define BATCH  8192

typedef float v4f __attribute__((ext_vector_type(4)));
typedef short v8s __attribute__((ext_vector_type(8)));

// ---------------- threefry2x32 (exact JAX semantics) ----------------
__device__ __forceinline__ uint32_t rotl32(uint32_t v, int d) {
  return (v << d) | (v >> (32 - d));
}

__device__ __forceinline__ void tf2x32(uint32_t k0, uint32_t k1,
                                       uint32_t x0, uint32_t x1,
                                       uint32_t& o0, uint32_t& o1) {
  uint32_t ks2 = k0 ^ k1 ^ 0x1BD11BDAu;
  x0 += k0; x1 += k1;
#define TFR4(a,b,c,d) \
  x0 += x1; x1 = rotl32(x1,a); x1 ^= x0; \
  x0 += x1; x1 = rotl32(x1,b); x1 ^= x0; \
  x0 += x1; x1 = rotl32(x1,c); x1 ^= x0; \
  x0 += x1; x1 = rotl32(x1,d); x1 ^= x0;
  TFR4(13,15,26,6)   x0 += k1;  x1 += ks2 + 1u;
  TFR4(17,29,16,24)  x0 += ks2; x1 += k0  + 2u;
  TFR4(13,15,26,6)   x0 += k0;  x1 += k1  + 3u;
  TFR4(17,29,16,24)  x0 += k1;  x1 += ks2 + 4u;
  TFR4(13,15,26,6)   x0 += ks2; x1 += k0  + 5u;
#undef TFR4
  o0 = x0; o1 = x1;
}

__device__ __forceinline__ float gumb_from_bits(uint32_t bits) {
  float f = __uint_as_float((bits >> 9) | 0x3f800000u) - 1.0f;
  float u = (f == 0.0f) ? 1.17549435e-38f : f;
  return -logf(-logf(u));
}

__device__ __forceinline__ uint32_t rbits32(uint32_t k0, uint32_t k1, uint32_t e) {
  uint32_t a, b;
  tf2x32(k0, k1, 0u, e, a, b);
  return a ^ b;
}

__global__ void gumbel_precompute(float2* __restrict__ g) {
  int idx = blockIdx.x * blockDim.x + threadIdx.x;
  if (idx >= NSITES * BATCH) return;
  int t = idx >> 13;
  int b = idx & (BATCH - 1);
  uint32_t kt0, kt1;
  tf2x32(0u, 1234u, 0u, (uint32_t)t, kt0, kt1);
  uint32_t r0 = rbits32(kt0, kt1, (uint32_t)(2 * b));
  uint32_t r1 = rbits32(kt0, kt1, (uint32_t)(2 * b + 1));
  g[idx] = make_float2(gumb_from_bits(r0), gumb_from_bits(r1));
}

// --------- Wh -> 3-term truncated-bf16 split, transposed [col][j] ---------
__global__ void split_wht(const float* __restrict__ Wh, ushort* __restrict__ w0,
                          ushort* __restrict__ w1, ushort* __restrict__ w2) {
  int idx = blockIdx.x * 256 + threadIdx.x;   // 0..12287 = col*64 + j
  if (idx >= 192 * 64) return;
  int col = idx >> 6;
  int j   = idx & 63;
  float w = Wh[j * 192 + col];
  uint32_t u0 = __float_as_uint(w) & 0xffff0000u;
  float f0 = __uint_as_float(u0);
  float r1 = w - f0;
  uint32_t u1 = __float_as_uint(r1) & 0xffff0000u;
  float f1 = __uint_as_float(u1);
  float r2 = r1 - f1;
  uint32_t u2 = __float_as_uint(r2) & 0xffff0000u;
  w0[idx] = (ushort)(u0 >> 16);
  w1[idx] = (ushort)(u1 >> 16);
  w2[idx] = (ushort)(u2 >> 16);
}

// XLA's logistic_expander form: 0.5 + 0.5*tanh(0.5*x)
__device__ __forceinline__ float sigmoid_xla(float x) {
  return 0.5f + 0.5f * tanhf(0.5f * x);
}

#define MF(A_, B_, C_) __builtin_amdgcn_mfma_f32_16x16x32_bf16((A_), (B_), (C_), 0, 0, 0)
#define F4(v_, r_) (((const float*)&(v_))[r_])

// ============ MFMA kernel v5: de-duplicated cross-wave work ===============
// 16 samples/block, 4 waves; wave w owns unit-group 16w..16w+15 (tiles
// {w,4+w,8+w}).  NEW vs R11:
//  - h's 3-term bf16 SPLITS are computed once by the owning wave and shared
//    via LDS in B-fragment layout (identical bits; readers just ds_read).
//  - logits/softmax/decision computed ONLY by wave 0 (the same instruction
//    sequence as R11, once instead of 4x); decision broadcast via LDS.
//  - two barriers/step; wave0's softmax overlaps other waves' MFMA issue.
// All FP ops keep R11's exact operand order -> absmax 0.0 by construction.
__global__ __launch_bounds__(256)
void rnn_mfma5(const float* __restrict__ Wi, const float* __restrict__ bb,
               const float* __restrict__ Wd, const float* __restrict__ bd,
               const ushort* __restrict__ w0p, const ushort* __restrict__ w1p,
               const ushort* __restrict__ w2p, const float2* __restrict__ g,
               float* __restrict__ out_s, float* __restrict__ out_lp) {
  // bf16 splits of h in B-frag layout: [L][kc][hg][s][8 shorts]
  __shared__ __align__(16) ushort bsp[3 * 2 * 4 * 16 * 8];   // 6 KiB
  __shared__ __align__(16) float hf32[16 * 68];              // f32 h (logits)
  __shared__ int scs[16];                                    // decisions
  __shared__ __align__(16) float c0zr[128];
  __shared__ __align__(16) float bh0a[64], bh1a[64];
  __shared__ __align__(16) float cw0[192], cw1[192];
  __shared__ __align__(16) float wd0a[64], wd1a[64];

  const int tid = threadIdx.x;
  const int l = tid & 63, s = l & 15, hi = l >> 4;
  const int w = tid >> 6;
  const int base = blockIdx.x * 16;

  if (tid < 64) {
    c0zr[tid] = bb[tid] + bb[192 + tid];
    c0zr[tid + 64] = bb[tid + 64] + bb[256 + tid];
    bh0a[tid] = bb[128 + tid];
    bh1a[tid] = bb[320 + tid];
    wd0a[tid] = Wd[2 * tid];
    wd1a[tid] = Wd[2 * tid + 1];
    cw0[tid] = Wi[tid]; cw0[tid + 64] = Wi[tid + 64]; cw0[tid + 128] = Wi[tid + 128];
    cw1[tid] = Wi[192 + tid]; cw1[tid + 64] = Wi[256 + tid]; cw1[tid + 128] = Wi[320 + tid];
  }
  for (int k = tid; k < 1536; k += 256) ((uint*)bsp)[k] = 0;  // h(-1)=0 splits
  __syncthreads();

  // ---- A fragments: 3 splits x 3 tiles {w,4+w,8+w} x 2 k-chunks ----
  v8s A0[3][2], A1[3][2], A2[3][2];
#pragma unroll
  for (int i3 = 0; i3 < 3; ++i3) {
    const int tile = w + 4 * i3;
#pragma unroll
    for (int kc = 0; kc < 2; ++kc) {
      const int off = (16 * tile + s) * 64 + 32 * kc + 8 * hi;
      A0[i3][kc] = *reinterpret_cast<const v8s*>(w0p + off);
      A1[i3][kc] = *reinterpret_cast<const v8s*>(w1p + off);
      A2[i3][kc] = *reinterpret_cast<const v8s*>(w2p + off);
    }
  }

  const float bd0 = bd[0], bd1 = bd[1];
  const int u0i = 16 * w + 4 * hi;        // this wave's gate-unit group
  const float4 czv  = *reinterpret_cast<const float4*>(&c0zr[u0i]);
  const float4 crv  = *reinterpret_cast<const float4*>(&c0zr[64 + u0i]);
  const float4 bh0v = *reinterpret_cast<const float4*>(&bh0a[u0i]);
  const float4 bh1v = *reinterpret_cast<const float4*>(&bh1a[u0i]);
  const float4 wz0  = *reinterpret_cast<const float4*>(&cw0[u0i]);
  const float4 wz1  = *reinterpret_cast<const float4*>(&cw1[u0i]);
  const float4 wr0  = *reinterpret_cast<const float4*>(&cw0[64 + u0i]);
  const float4 wr1  = *reinterpret_cast<const float4*>(&cw1[64 + u0i]);
  const float4 wh0  = *reinterpret_cast<const float4*>(&cw0[128 + u0i]);
  const float4 wh1  = *reinterpret_cast<const float4*>(&cw1[128 + u0i]);

  // LDS pointers (shorts): read = lane's B-frag row; write = owned unit slot
  const ushort* rbp = bsp + hi * 128 + s * 8;        // + (L*2+kc)*512
  const int kcw = w >> 1;
  const int hg  = (2 * w + (hi >> 1)) & 3;
  const int i0  = (hi & 1) * 4;
  ushort* wbp = bsp + kcw * 512 + hg * 128 + s * 8 + i0;  // + L*1024

  float hreg[4] = {0.0f, 0.0f, 0.0f, 0.0f};
  float lp = 0.0f;
  float2 gcur;
  if (w == 0) gcur = g[base + s];        // gumbel for decision(0)

  for (int t = 0; t < NSITES; ++t) {
    // ---- phase A: B-frags (splits of h(t-1)) + MFMA; wave0: decision(t-1)
    v8s B0[2], B1[2], B2[2];
#pragma unroll
    for (int kc = 0; kc < 2; ++kc) {
      B0[kc] = *reinterpret_cast<const v8s*>(rbp + kc * 512);
      B1[kc] = *reinterpret_cast<const v8s*>(rbp + 1024 + kc * 512);
      B2[kc] = *reinterpret_cast<const v8s*>(rbp + 2048 + kc * 512);
    }

    v4f acc[3];
#pragma unroll
    for (int i3 = 0; i3 < 3; ++i3) {
      v4f a = {0.0f, 0.0f, 0.0f, 0.0f};
#pragma unroll
      for (int kc = 0; kc < 2; ++kc) a = MF(A2[i3][kc], B2[kc], a);
#pragma unroll
      for (int kc = 0; kc < 2; ++kc) a = MF(A2[i3][kc], B1[kc], a);
#pragma unroll
      for (int kc = 0; kc < 2; ++kc) a = MF(A1[i3][kc], B2[kc], a);
#pragma unroll
      for (int kc = 0; kc < 2; ++kc) a = MF(A2[i3][kc], B0[kc], a);
#pragma unroll
      for (int kc = 0; kc < 2; ++kc) a = MF(A0[i3][kc], B2[kc], a);
#pragma unroll
      for (int kc = 0; kc < 2; ++kc) a = MF(A1[i3][kc], B1[kc], a);
#pragma unroll
      for (int kc = 0; kc < 2; ++kc) a = MF(A1[i3][kc], B0[kc], a);
#pragma unroll
      for (int kc = 0; kc < 2; ++kc) a = MF(A0[i3][kc], B1[kc], a);
#pragma unroll
      for (int kc = 0; kc < 2; ++kc) a = MF(A0[i3][kc], B0[kc], a);
      acc[i3] = a;
    }

    if (t > 0 && w == 0) {
      // logits from hf32 = h(t-1): exact R11 chain (mt asc, r asc, hi tree)
      float pl0 = 0.0f, pl1 = 0.0f;
#pragma unroll
      for (int mt = 0; mt < 4; ++mt) {
        const int ui = 16 * mt + 4 * hi;
        const float4 hv4  = *reinterpret_cast<const float4*>(&hf32[s * 68 + ui]);
        const float4 wdl0 = *reinterpret_cast<const float4*>(&wd0a[ui]);
        const float4 wdl1 = *reinterpret_cast<const float4*>(&wd1a[ui]);
#pragma unroll
        for (int r = 0; r < 4; ++r) {
          pl0 = fmaf(F4(hv4, r), F4(wdl0, r), pl0);
          pl1 = fmaf(F4(hv4, r), F4(wdl1, r), pl1);
        }
      }
      pl0 += __shfl_xor(pl0, 16, 64);
      pl0 += __shfl_xor(pl0, 32, 64);
      pl1 += __shfl_xor(pl1, 16, 64);
      pl1 += __shfl_xor(pl1, 32, 64);
      const float l0 = pl0 + bd0, l1 = pl1 + bd1;

      const float mmax = fmaxf(l0, l1);
      const float sh0 = l0 - mmax, sh1 = l1 - mmax;
      const float lse = logf(expf(sh0) + expf(sh1));
      const int sc = ((l1 + gcur.y) > (l0 + gcur.x)) ? 1 : 0;
      lp += (sc ? sh1 : sh0) - lse;
      if (hi == 0) {
        scs[s] = sc;
        out_s[(size_t)(base + s) * NSITES + (t - 1)] = (float)sc;
      }
      gcur = g[t * BATCH + base + s];   // prefetch for decision(t)
    }

    __syncthreads();   // barrier2: decision(t-1) visible; B-reads complete

    // ---- gates for this wave's 16 units (identical math to R11) ----
    float selz[4], selr[4], selh[4];
    if (t == 0) {
#pragma unroll
      for (int r = 0; r < 4; ++r) { selz[r] = 0.0f; selr[r] = 0.0f; selh[r] = 0.0f; }
    } else {
      const int sv = scs[s];
#pragma unroll
      for (int r = 0; r < 4; ++r) {
        selz[r] = sv ? F4(wz1, r) : F4(wz0, r);
        selr[r] = sv ? F4(wr1, r) : F4(wr0, r);
        selh[r] = sv ? F4(wh1, r) : F4(wh0, r);
      }
    }

    float4 hstore;
    uint sp0[4], sp1[4], sp2[4];
#pragma unroll
    for (int r = 0; r < 4; ++r) {
      const float zin = acc[0][r] + F4(czv, r) + selz[r];
      const float rin = acc[1][r] + F4(crv, r) + selr[r];
      const float rhv = acc[2][r] + F4(bh1v, r);
      const float xhv = F4(bh0v, r) + selh[r];
      const float zg = sigmoid_xla(zin);
      const float rg = sigmoid_xla(rin);
      const float hg = tanhf(xhv + rg * rhv);
      const float hn = zg * hreg[r] + (1.0f - zg) * hg;
      hreg[r] = hn;
      ((float*)&hstore)[r] = hn;
      // 3-term truncated-bf16 split (same bits readers would compute)
      const uint u0 = __float_as_uint(hn) & 0xffff0000u;
      const float f0 = __uint_as_float(u0);
      const float r1f = hn - f0;
      const uint u1 = __float_as_uint(r1f) & 0xffff0000u;
      const float f1 = __uint_as_float(u1);
      const float r2f = r1f - f1;
      const uint u2 = __float_as_uint(r2f) & 0xffff0000u;
      sp0[r] = u0 >> 16; sp1[r] = u1 >> 16; sp2[r] = u2 >> 16;
    }
    *reinterpret_cast<float4*>(&hf32[s * 68 + u0i]) = hstore;
    {
      uint2 p;
      p.x = sp0[0] | (sp0[1] << 16); p.y = sp0[2] | (sp0[3] << 16);
      *reinterpret_cast<uint2*>(wbp) = p;
      p.x = sp1[0] | (sp1[1] << 16); p.y = sp1[2] | (sp1[3] << 16);
      *reinterpret_cast<uint2*>(wbp + 1024) = p;
      p.x = sp2[0] | (sp2[1] << 16); p.y = sp2[2] | (sp2[3] << 16);
      *reinterpret_cast<uint2*>(wbp + 2048) = p;
    }

    __syncthreads();   // barrier1: h(t) + splits visible
  }

  // ---- epilogue: decision(255) ----
  if (w == 0) {
    float pl0 = 0.0f, pl1 = 0.0f;
#pragma unroll
    for (int mt = 0; mt < 4; ++mt) {
      const int ui = 16 * mt + 4 * hi;
      const float4 hv4  = *reinterpret_cast<const float4*>(&hf32[s * 68 + ui]);
      const float4 wdl0 = *reinterpret_cast<const float4*>(&wd0a[ui]);
      const float4 wdl1 = *reinterpret_cast<const float4*>(&wd1a[ui]);
#pragma unroll
      for (int r = 0; r < 4; ++r) {
        pl0 = fmaf(F4(hv4, r), F4(wdl0, r), pl0);
        pl1 = fmaf(F4(hv4, r), F4(wdl1, r), pl1);
      }
    }
    pl0 += __shfl_xor(pl0, 16, 64);
    pl0 += __shfl_xor(pl0, 32, 64);
    pl1 += __shfl_xor(pl1, 16, 64);
    pl1 += __shfl_xor(pl1, 32, 64);
    const float l0 = pl0 + bd0, l1 = pl1 + bd1;
    const float mmax = fmaxf(l0, l1);
    const float sh0 = l0 - mmax, sh1 = l1 - mmax;
    const float lse = logf(expf(sh0) + expf(sh1));
    const int sc = ((l1 + gcur.y) > (l0 + gcur.x)) ? 1 : 0;
    lp += (sc ? sh1 : sh0) - lse;
    if (hi == 0) {
      out_s[(size_t)(base + s) * NSITES + (NSITES - 1)] = (float)sc;
      out_lp[base + s] = 0.5f * lp;
    }
  }
}

// ---------------- fallback (ws too small): proven bit-exact path ----------
__global__ __launch_bounds__(64)
void rnn_plain(const float* __restrict__ Wi, const float* __restrict__ Wh,
               const float* __restrict__ bb, const float* __restrict__ Wd,
               const float* __restrict__ bd,
               float* __restrict__ out_s, float* __restrict__ out_lp) {
  const int lane = threadIdx.x;
  const int b = blockIdx.x;

  float wz[NHID], wr[NHID], wh[NHID];
#pragma unroll
  for (int j = 0; j < NHID; ++j) {
    wz[j] = Wh[j * 192 + lane];
    wr[j] = Wh[j * 192 + 64 + lane];
    wh[j] = Wh[j * 192 + 128 + lane];
  }
  const float b1z = bb[192 + lane];
  const float b1r = bb[192 + 64 + lane];
  const float b1h = bb[192 + 128 + lane];
  const float m0z = bb[lane], m0r = bb[64 + lane], m0h = bb[128 + lane];
  const float m1z = Wi[lane] + m0z, m1r = Wi[64 + lane] + m0r, m1h = Wi[128 + lane] + m0h;
  const float m2z = Wi[192 + lane] + m0z, m2r = Wi[192 + 64 + lane] + m0r,
              m2h = Wi[192 + 128 + lane] + m0h;
  const float wd0 = Wd[lane * 2 + 0], wd1 = Wd[lane * 2 + 1];
  const float bd0 = bd[0], bd1 = bd[1];

  float h = 0.0f, lpsum = 0.0f;
  float xz = m0z, xr = m0r, xh = m0h;

  for (int t = 0; t < NSITES; ++t) {
    uint32_t kt0, kt1;
    tf2x32(0u, 1234u, 0u, (uint32_t)t, kt0, kt1);
    const float g0 = gumb_from_bits(rbits32(kt0, kt1, (uint32_t)(2 * b)));
    const float g1 = gumb_from_bits(rbits32(kt0, kt1, (uint32_t)(2 * b + 1)));

    float az = 0.0f, ar = 0.0f, ah = 0.0f;
#pragma unroll
    for (int j = 0; j < NHID; ++j) {
      const float hj = __int_as_float(__builtin_amdgcn_readlane(__float_as_int(h), j));
      az = fmaf(hj, wz[j], az);
      ar = fmaf(hj, wr[j], ar);
      ah = fmaf(hj, wh[j], ah);
    }
    const float rz = az + b1z, rr = ar + b1r, rh = ah + b1h;
    const float zg = sigmoid_xla(xz + rz);
    const float rg = sigmoid_xla(xr + rr);
    const float hg = tanhf(xh + rg * rh);
    h = zg * h + (1.0f - zg) * hg;

    float p0 = h * wd0, p1 = h * wd1;
#pragma unroll
    for (int off = 32; off > 0; off >>= 1) {
      p0 += __shfl_xor(p0, off, 64);
      p1 += __shfl_xor(p1, off, 64);
    }
    const float l0 = p0 + bd0, l1 = p1 + bd1;
    const float mmax = fmaxf(l0, l1);
    const float sh0 = l0 - mmax, sh1 = l1 - mmax;
    const float lse = logf(expf(sh0) + expf(sh1));
    const int si = ((l1 + g1) > (l0 + g0)) ? 1 : 0;
    lpsum += (si ? sh1 : sh0) - lse;
    if (lane == 0) out_s[(size_t)b * NSITES + t] = (float)si;
    xz = si ? m2z : m1z;
    xr = si ? m2r : m1r;
    xh = si ? m2h : m1h;
  }

  if (lane == 0) out_lp[b] = 0.5f * lpsum;
}

extern "C" void kernel_launch(void* const* d_in, const int* in_sizes, int n_in,
                              void* d_out, int out_size, void* d_ws, size_t ws_size,
                              hipStream_t stream) {
  const float* Wi = (const float*)d_in[1];
  const float* Wh = (const float*)d_in[2];
  const float* bb = (const float*)d_in[3];
  const float* Wd = (const float*)d_in[4];
  const float* bd = (const float*)d_in[5];

  float* out    = (float*)d_out;
  float* out_s  = out;                           // [8192][256]
  float* out_lp = out + (size_t)BATCH * NSITES;  // [8192]

  const size_t gbytes = (size_t)NSITES * BATCH * sizeof(float2);  // 16 MiB
  const size_t wb = (size_t)192 * 64 * sizeof(ushort);            // 24 KiB

  if (ws_size >= gbytes + 3 * wb) {
    float2* g  = (float2*)d_ws;
    ushort* w0 = (ushort*)((char*)d_ws + gbytes);
    ushort* w1 = w0 + 192 * 64;
    ushort* w2 = w1 + 192 * 64;
    gumbel_precompute<<<(NSITES * BATCH) / 256, 256, 0, stream>>>(g);
    split_wht<<<48, 256, 0, stream>>>(Wh, w0, w1, w2);
    rnn_mfma5<<<BATCH / 16, 256, 0, stream>>>(Wi, bb, Wd, bd, w0, w1, w2, g, out_s, out_lp);
  } else {
    rnn_plain<<<BATCH, 64, 0, stream>>>(Wi, Wh, bb, Wd, bd, out_s, out_lp);
  }
}

// Round 13
// 463.834 us; speedup vs baseline: 1.3859x; 1.3859x over previous
//
#include <hip/hip_runtime.h>
#include <stdint.h>

#define NSITES 256
#define NHID   64
#define BATCH  8192

typedef float v4f __attribute__((ext_vector_type(4)));
typedef short v8s __attribute__((ext_vector_type(8)));

// ---------------- threefry2x32 (exact JAX semantics) ----------------
__device__ __forceinline__ uint32_t rotl32(uint32_t v, int d) {
  return (v << d) | (v >> (32 - d));
}

__device__ __forceinline__ void tf2x32(uint32_t k0, uint32_t k1,
                                       uint32_t x0, uint32_t x1,
                                       uint32_t& o0, uint32_t& o1) {
  uint32_t ks2 = k0 ^ k1 ^ 0x1BD11BDAu;
  x0 += k0; x1 += k1;
#define TFR4(a,b,c,d) \
  x0 += x1; x1 = rotl32(x1,a); x1 ^= x0; \
  x0 += x1; x1 = rotl32(x1,b); x1 ^= x0; \
  x0 += x1; x1 = rotl32(x1,c); x1 ^= x0; \
  x0 += x1; x1 = rotl32(x1,d); x1 ^= x0;
  TFR4(13,15,26,6)   x0 += k1;  x1 += ks2 + 1u;
  TFR4(17,29,16,24)  x0 += ks2; x1 += k0  + 2u;
  TFR4(13,15,26,6)   x0 += k0;  x1 += k1  + 3u;
  TFR4(17,29,16,24)  x0 += k1;  x1 += ks2 + 4u;
  TFR4(13,15,26,6)   x0 += ks2; x1 += k0  + 5u;
#undef TFR4
  o0 = x0; o1 = x1;
}

__device__ __forceinline__ float gumb_from_bits(uint32_t bits) {
  float f = __uint_as_float((bits >> 9) | 0x3f800000u) - 1.0f;
  float u = (f == 0.0f) ? 1.17549435e-38f : f;
  return -logf(-logf(u));
}

__device__ __forceinline__ uint32_t rbits32(uint32_t k0, uint32_t k1, uint32_t e) {
  uint32_t a, b;
  tf2x32(k0, k1, 0u, e, a, b);
  return a ^ b;
}

__global__ void gumbel_precompute(float2* __restrict__ g) {
  int idx = blockIdx.x * blockDim.x + threadIdx.x;
  if (idx >= NSITES * BATCH) return;
  int t = idx >> 13;
  int b = idx & (BATCH - 1);
  uint32_t kt0, kt1;
  tf2x32(0u, 1234u, 0u, (uint32_t)t, kt0, kt1);
  uint32_t r0 = rbits32(kt0, kt1, (uint32_t)(2 * b));
  uint32_t r1 = rbits32(kt0, kt1, (uint32_t)(2 * b + 1));
  g[idx] = make_float2(gumb_from_bits(r0), gumb_from_bits(r1));
}

// ------ [WhT ; WdT ; zeros] (208 rows x 64) -> 3-term truncated-bf16 ------
// rows 0-191: WhT[gate*64+unit][j]; rows 192-193: Wd columns; 194-207: zero.
__global__ void split_awt(const float* __restrict__ Wh, const float* __restrict__ Wd,
                          ushort* __restrict__ w0, ushort* __restrict__ w1,
                          ushort* __restrict__ w2) {
  int idx = blockIdx.x * 256 + threadIdx.x;   // 0..13311 = col*64 + j
  if (idx >= 208 * 64) return;
  int col = idx >> 6;
  int j   = idx & 63;
  float w;
  if (col < 192)      w = Wh[j * 192 + col];
  else if (col < 194) w = Wd[j * 2 + (col - 192)];
  else                w = 0.0f;
  uint32_t u0 = __float_as_uint(w) & 0xffff0000u;
  float f0 = __uint_as_float(u0);
  float r1 = w - f0;
  uint32_t u1 = __float_as_uint(r1) & 0xffff0000u;
  float f1 = __uint_as_float(u1);
  float r2 = r1 - f1;
  uint32_t u2 = __float_as_uint(r2) & 0xffff0000u;
  w0[idx] = (ushort)(u0 >> 16);
  w1[idx] = (ushort)(u1 >> 16);
  w2[idx] = (ushort)(u2 >> 16);
}

// XLA's logistic_expander form: 0.5 + 0.5*tanh(0.5*x)
__device__ __forceinline__ float sigmoid_xla(float x) {
  return 0.5f + 0.5f * tanhf(0.5f * x);
}

#define MF(A_, B_, C_) __builtin_amdgcn_mfma_f32_16x16x32_bf16((A_), (B_), (C_), 0, 0, 0)
#define F4(v_, r_) (((const float*)&(v_))[r_])

// ============ MFMA kernel v6: one barrier/step, MFMA logits tile ==========
// 16 samples/block, 4 waves; wave w owns unit-tiles {w,4+w,8+w} (exact R11
// 9-product chains -> h trajectory bit-identical).  NEW: logits tile (rows
// 192-207 = [Wd^T; 0]) computed by EVERY wave from the same B-frags -> its
// lanes 0-15 hold l0/l1 (D rows 0/1) and decide locally; one __shfl spreads
// the decision wave-internally.  B-splits double-buffered in LDS -> ONE
// barrier per step.  Iteration t: decision(t-1) + gates(t).
__global__ __launch_bounds__(256, 2)
void rnn_mfma6(const float* __restrict__ Wi, const float* __restrict__ bb,
               const float* __restrict__ bd,
               const ushort* __restrict__ w0p, const ushort* __restrict__ w1p,
               const ushort* __restrict__ w2p, const float2* __restrict__ g,
               float* __restrict__ out_s, float* __restrict__ out_lp) {
  __shared__ __align__(16) ushort bsp[2][3072];   // h splits, B-frag layout
  __shared__ __align__(16) float c0zr[128];
  __shared__ __align__(16) float bh0a[64], bh1a[64];
  __shared__ __align__(16) float cw0[192], cw1[192];

  const int tid = threadIdx.x;
  const int l = tid & 63, s = l & 15, hi = l >> 4;
  const int w = tid >> 6;
  const int base = blockIdx.x * 16;

  if (tid < 64) {
    c0zr[tid] = bb[tid] + bb[192 + tid];
    c0zr[tid + 64] = bb[tid + 64] + bb[256 + tid];
    bh0a[tid] = bb[128 + tid];
    bh1a[tid] = bb[320 + tid];
    cw0[tid] = Wi[tid]; cw0[tid + 64] = Wi[tid + 64]; cw0[tid + 128] = Wi[tid + 128];
    cw1[tid] = Wi[192 + tid]; cw1[tid + 64] = Wi[256 + tid]; cw1[tid + 128] = Wi[320 + tid];
  }
  for (int k = tid; k < 1536; k += 256) ((uint*)bsp[0])[k] = 0u;  // h(-1)=0
  __syncthreads();

  // ---- A fragments: unit tiles {w,4+w,8+w} + logits tile 12, 3 splits ----
  v8s A0[3][2], A1[3][2], A2[3][2];
#pragma unroll
  for (int i3 = 0; i3 < 3; ++i3) {
    const int tile = w + 4 * i3;
#pragma unroll
    for (int kc = 0; kc < 2; ++kc) {
      const int off = (16 * tile + s) * 64 + 32 * kc + 8 * hi;
      A0[i3][kc] = *reinterpret_cast<const v8s*>(w0p + off);
      A1[i3][kc] = *reinterpret_cast<const v8s*>(w1p + off);
      A2[i3][kc] = *reinterpret_cast<const v8s*>(w2p + off);
    }
  }
  v8s L0[2], L1[2], L2[2];
#pragma unroll
  for (int kc = 0; kc < 2; ++kc) {
    const int off = (192 + s) * 64 + 32 * kc + 8 * hi;   // tile 12
    L0[kc] = *reinterpret_cast<const v8s*>(w0p + off);
    L1[kc] = *reinterpret_cast<const v8s*>(w1p + off);
    L2[kc] = *reinterpret_cast<const v8s*>(w2p + off);
  }

  const float bd0 = bd[0], bd1 = bd[1];
  const int u0i = 16 * w + 4 * hi;        // this wave's gate-unit group
  const float4 czv  = *reinterpret_cast<const float4*>(&c0zr[u0i]);
  const float4 crv  = *reinterpret_cast<const float4*>(&c0zr[64 + u0i]);
  const float4 bh0v = *reinterpret_cast<const float4*>(&bh0a[u0i]);
  const float4 bh1v = *reinterpret_cast<const float4*>(&bh1a[u0i]);
  const float4 wz0  = *reinterpret_cast<const float4*>(&cw0[u0i]);
  const float4 wz1  = *reinterpret_cast<const float4*>(&cw1[u0i]);
  const float4 wr0  = *reinterpret_cast<const float4*>(&cw0[64 + u0i]);
  const float4 wr1  = *reinterpret_cast<const float4*>(&cw1[64 + u0i]);
  const float4 wh0  = *reinterpret_cast<const float4*>(&cw0[128 + u0i]);
  const float4 wh1  = *reinterpret_cast<const float4*>(&cw1[128 + u0i]);

  // B-split write slot (same mapping as R12, now double-buffered)
  const int kcw = w >> 1;
  const int hgw = (2 * w + (hi >> 1)) & 3;
  const int i0  = (hi & 1) * 4;

  float hreg[4] = {0.0f, 0.0f, 0.0f, 0.0f};
  float lp = 0.0f;
  float2 gcur = make_float2(0.0f, 0.0f), gnext = make_float2(0.0f, 0.0f);
  int p = 0;

  for (int t = 0; t <= NSITES; ++t) {
    // prefetch gumbel for NEXT iteration's decision (hidden under this step)
    if (t < NSITES && hi == 0) gnext = g[t * BATCH + base + s];

    // ---- B fragments of h(t-1) from LDS ----
    const ushort* rb = bsp[p] + hi * 128 + s * 8;
    v8s B0[2], B1[2], B2[2];
#pragma unroll
    for (int kc = 0; kc < 2; ++kc) {
      B0[kc] = *reinterpret_cast<const v8s*>(rb + kc * 512);
      B1[kc] = *reinterpret_cast<const v8s*>(rb + 1024 + kc * 512);
      B2[kc] = *reinterpret_cast<const v8s*>(rb + 2048 + kc * 512);
    }

    // ---- logits tile (6 products, low -> high) ----
    v4f al = {0.0f, 0.0f, 0.0f, 0.0f};
#pragma unroll
    for (int kc = 0; kc < 2; ++kc) al = MF(L1[kc], B1[kc], al);
#pragma unroll
    for (int kc = 0; kc < 2; ++kc) al = MF(L2[kc], B0[kc], al);
#pragma unroll
    for (int kc = 0; kc < 2; ++kc) al = MF(L0[kc], B2[kc], al);
#pragma unroll
    for (int kc = 0; kc < 2; ++kc) al = MF(L1[kc], B0[kc], al);
#pragma unroll
    for (int kc = 0; kc < 2; ++kc) al = MF(L0[kc], B1[kc], al);
#pragma unroll
    for (int kc = 0; kc < 2; ++kc) al = MF(L0[kc], B0[kc], al);

    // ---- decision(t-1): lanes 0-15 hold l0 (row0) / l1 (row1) ----
    int scd = 0;
    if (t > 0) {
      const float l0 = al[0] + bd0, l1 = al[1] + bd1;
      const float mmax = fmaxf(l0, l1);
      const float sh0 = l0 - mmax, sh1 = l1 - mmax;
      const float lse = logf(expf(sh0) + expf(sh1));
      scd = ((l1 + gcur.y) > (l0 + gcur.x)) ? 1 : 0;
      lp += (scd ? sh1 : sh0) - lse;
      if (tid < 16) out_s[(size_t)(base + s) * NSITES + (t - 1)] = (float)scd;
    }

    if (t < NSITES) {
      const int scb = __shfl(scd, s, 64);   // decision(t-1), all lanes

      // ---- unit tiles: exact R11/R12 9-product chains ----
      v4f acc[3];
#pragma unroll
      for (int i3 = 0; i3 < 3; ++i3) {
        v4f a = {0.0f, 0.0f, 0.0f, 0.0f};
#pragma unroll
        for (int kc = 0; kc < 2; ++kc) a = MF(A2[i3][kc], B2[kc], a);
#pragma unroll
        for (int kc = 0; kc < 2; ++kc) a = MF(A2[i3][kc], B1[kc], a);
#pragma unroll
        for (int kc = 0; kc < 2; ++kc) a = MF(A1[i3][kc], B2[kc], a);
#pragma unroll
        for (int kc = 0; kc < 2; ++kc) a = MF(A2[i3][kc], B0[kc], a);
#pragma unroll
        for (int kc = 0; kc < 2; ++kc) a = MF(A0[i3][kc], B2[kc], a);
#pragma unroll
        for (int kc = 0; kc < 2; ++kc) a = MF(A1[i3][kc], B1[kc], a);
#pragma unroll
        for (int kc = 0; kc < 2; ++kc) a = MF(A1[i3][kc], B0[kc], a);
#pragma unroll
        for (int kc = 0; kc < 2; ++kc) a = MF(A0[i3][kc], B1[kc], a);
#pragma unroll
        for (int kc = 0; kc < 2; ++kc) a = MF(A0[i3][kc], B0[kc], a);
        acc[i3] = a;
      }

      // ---- gates for this wave's 16 units (identical math) ----
      float selz[4], selr[4], selh[4];
      if (t == 0) {
#pragma unroll
        for (int r = 0; r < 4; ++r) { selz[r] = 0.0f; selr[r] = 0.0f; selh[r] = 0.0f; }
      } else {
#pragma unroll
        for (int r = 0; r < 4; ++r) {
          selz[r] = scb ? F4(wz1, r) : F4(wz0, r);
          selr[r] = scb ? F4(wr1, r) : F4(wr0, r);
          selh[r] = scb ? F4(wh1, r) : F4(wh0, r);
        }
      }

      uint sp0[4], sp1[4], sp2[4];
#pragma unroll
      for (int r = 0; r < 4; ++r) {
        const float zin = acc[0][r] + F4(czv, r) + selz[r];
        const float rin = acc[1][r] + F4(crv, r) + selr[r];
        const float rhv = acc[2][r] + F4(bh1v, r);
        const float xhv = F4(bh0v, r) + selh[r];
        const float zg = sigmoid_xla(zin);
        const float rg = sigmoid_xla(rin);
        const float hg = tanhf(xhv + rg * rhv);
        const float hn = zg * hreg[r] + (1.0f - zg) * hg;
        hreg[r] = hn;
        // 3-term truncated-bf16 split (same bits as readers would compute)
        const uint u0 = __float_as_uint(hn) & 0xffff0000u;
        const float f0 = __uint_as_float(u0);
        const float r1f = hn - f0;
        const uint u1 = __float_as_uint(r1f) & 0xffff0000u;
        const float f1 = __uint_as_float(u1);
        const float r2f = r1f - f1;
        const uint u2 = __float_as_uint(r2f) & 0xffff0000u;
        sp0[r] = u0 >> 16; sp1[r] = u1 >> 16; sp2[r] = u2 >> 16;
      }
      ushort* wb = bsp[p ^ 1] + kcw * 512 + hgw * 128 + s * 8 + i0;
      {
        uint2 q;
        q.x = sp0[0] | (sp0[1] << 16); q.y = sp0[2] | (sp0[3] << 16);
        *reinterpret_cast<uint2*>(wb) = q;
        q.x = sp1[0] | (sp1[1] << 16); q.y = sp1[2] | (sp1[3] << 16);
        *reinterpret_cast<uint2*>(wb + 1024) = q;
        q.x = sp2[0] | (sp2[1] << 16); q.y = sp2[2] | (sp2[3] << 16);
        *reinterpret_cast<uint2*>(wb + 2048) = q;
      }
    }

    __syncthreads();   // h(t) splits visible; reads of bsp[p] complete
    p ^= 1;
    gcur = gnext;
  }

  if (tid < 16) out_lp[base + s] = 0.5f * lp;
}

// ---------------- fallback (ws too small): proven bit-exact path ----------
__global__ __launch_bounds__(64)
void rnn_plain(const float* __restrict__ Wi, const float* __restrict__ Wh,
               const float* __restrict__ bb, const float* __restrict__ Wd,
               const float* __restrict__ bd,
               float* __restrict__ out_s, float* __restrict__ out_lp) {
  const int lane = threadIdx.x;
  const int b = blockIdx.x;

  float wz[NHID], wr[NHID], wh[NHID];
#pragma unroll
  for (int j = 0; j < NHID; ++j) {
    wz[j] = Wh[j * 192 + lane];
    wr[j] = Wh[j * 192 + 64 + lane];
    wh[j] = Wh[j * 192 + 128 + lane];
  }
  const float b1z = bb[192 + lane];
  const float b1r = bb[192 + 64 + lane];
  const float b1h = bb[192 + 128 + lane];
  const float m0z = bb[lane], m0r = bb[64 + lane], m0h = bb[128 + lane];
  const float m1z = Wi[lane] + m0z, m1r = Wi[64 + lane] + m0r, m1h = Wi[128 + lane] + m0h;
  const float m2z = Wi[192 + lane] + m0z, m2r = Wi[192 + 64 + lane] + m0r,
              m2h = Wi[192 + 128 + lane] + m0h;
  const float wd0 = Wd[lane * 2 + 0], wd1 = Wd[lane * 2 + 1];
  const float bd0 = bd[0], bd1 = bd[1];

  float h = 0.0f, lpsum = 0.0f;
  float xz = m0z, xr = m0r, xh = m0h;

  for (int t = 0; t < NSITES; ++t) {
    uint32_t kt0, kt1;
    tf2x32(0u, 1234u, 0u, (uint32_t)t, kt0, kt1);
    const float g0 = gumb_from_bits(rbits32(kt0, kt1, (uint32_t)(2 * b)));
    const float g1 = gumb_from_bits(rbits32(kt0, kt1, (uint32_t)(2 * b + 1)));

    float az = 0.0f, ar = 0.0f, ah = 0.0f;
#pragma unroll
    for (int j = 0; j < NHID; ++j) {
      const float hj = __int_as_float(__builtin_amdgcn_readlane(__float_as_int(h), j));
      az = fmaf(hj, wz[j], az);
      ar = fmaf(hj, wr[j], ar);
      ah = fmaf(hj, wh[j], ah);
    }
    const float rz = az + b1z, rr = ar + b1r, rh = ah + b1h;
    const float zg = sigmoid_xla(xz + rz);
    const float rg = sigmoid_xla(xr + rr);
    const float hg = tanhf(xh + rg * rh);
    h = zg * h + (1.0f - zg) * hg;

    float p0 = h * wd0, p1 = h * wd1;
#pragma unroll
    for (int off = 32; off > 0; off >>= 1) {
      p0 += __shfl_xor(p0, off, 64);
      p1 += __shfl_xor(p1, off, 64);
    }
    const float l0 = p0 + bd0, l1 = p1 + bd1;
    const float mmax = fmaxf(l0, l1);
    const float sh0 = l0 - mmax, sh1 = l1 - mmax;
    const float lse = logf(expf(sh0) + expf(sh1));
    const int si = ((l1 + g1) > (l0 + g0)) ? 1 : 0;
    lpsum += (si ? sh1 : sh0) - lse;
    if (lane == 0) out_s[(size_t)b * NSITES + t] = (float)si;
    xz = si ? m2z : m1z;
    xr = si ? m2r : m1r;
    xh = si ? m2h : m1h;
  }

  if (lane == 0) out_lp[b] = 0.5f * lpsum;
}

extern "C" void kernel_launch(void* const* d_in, const int* in_sizes, int n_in,
                              void* d_out, int out_size, void* d_ws, size_t ws_size,
                              hipStream_t stream) {
  const float* Wi = (const float*)d_in[1];
  const float* Wh = (const float*)d_in[2];
  const float* bb = (const float*)d_in[3];
  const float* Wd = (const float*)d_in[4];
  const float* bd = (const float*)d_in[5];

  float* out    = (float*)d_out;
  float* out_s  = out;                           // [8192][256]
  float* out_lp = out + (size_t)BATCH * NSITES;  // [8192]

  const size_t gbytes = (size_t)NSITES * BATCH * sizeof(float2);  // 16 MiB
  const size_t wb = (size_t)208 * 64 * sizeof(ushort);            // 26 KiB

  if (ws_size >= gbytes + 3 * wb) {
    float2* g  = (float2*)d_ws;
    ushort* w0 = (ushort*)((char*)d_ws + gbytes);
    ushort* w1 = w0 + 208 * 64;
    ushort* w2 = w1 + 208 * 64;
    gumbel_precompute<<<(NSITES * BATCH) / 256, 256, 0, stream>>>(g);
    split_awt<<<(208 * 64 + 255) / 256, 256, 0, stream>>>(Wh, Wd, w0, w1, w2);
    rnn_mfma6<<<BATCH / 16, 256, 0, stream>>>(Wi, bb, bd, w0, w1, w2, g, out_s, out_lp);
  } else {
    rnn_plain<<<BATCH, 64, 0, stream>>>(Wi, Wh, bb, Wd, bd, out_s, out_lp);
  }
}

// Round 14
// 421.420 us; speedup vs baseline: 1.5254x; 1.1006x over previous
//
#include <hip/hip_runtime.h>
#include <stdint.h>

#define NSITES 256
#define NHID   64
#define BATCH  8192

typedef float v4f __attribute__((ext_vector_type(4)));
typedef short v8s __attribute__((ext_vector_type(8)));

// ---------------- threefry2x32 (exact JAX semantics) ----------------
__device__ __forceinline__ uint32_t rotl32(uint32_t v, int d) {
  return (v << d) | (v >> (32 - d));
}

__device__ __forceinline__ void tf2x32(uint32_t k0, uint32_t k1,
                                       uint32_t x0, uint32_t x1,
                                       uint32_t& o0, uint32_t& o1) {
  uint32_t ks2 = k0 ^ k1 ^ 0x1BD11BDAu;
  x0 += k0; x1 += k1;
#define TFR4(a,b,c,d) \
  x0 += x1; x1 = rotl32(x1,a); x1 ^= x0; \
  x0 += x1; x1 = rotl32(x1,b); x1 ^= x0; \
  x0 += x1; x1 = rotl32(x1,c); x1 ^= x0; \
  x0 += x1; x1 = rotl32(x1,d); x1 ^= x0;
  TFR4(13,15,26,6)   x0 += k1;  x1 += ks2 + 1u;
  TFR4(17,29,16,24)  x0 += ks2; x1 += k0  + 2u;
  TFR4(13,15,26,6)   x0 += k0;  x1 += k1  + 3u;
  TFR4(17,29,16,24)  x0 += k1;  x1 += ks2 + 4u;
  TFR4(13,15,26,6)   x0 += ks2; x1 += k0  + 5u;
#undef TFR4
  o0 = x0; o1 = x1;
}

__device__ __forceinline__ float gumb_from_bits(uint32_t bits) {
  float f = __uint_as_float((bits >> 9) | 0x3f800000u) - 1.0f;
  float u = (f == 0.0f) ? 1.17549435e-38f : f;
  return -logf(-logf(u));
}

__device__ __forceinline__ uint32_t rbits32(uint32_t k0, uint32_t k1, uint32_t e) {
  uint32_t a, b;
  tf2x32(k0, k1, 0u, e, a, b);
  return a ^ b;
}

__global__ void gumbel_precompute(float2* __restrict__ g) {
  int idx = blockIdx.x * blockDim.x + threadIdx.x;
  if (idx >= NSITES * BATCH) return;
  int t = idx >> 13;
  int b = idx & (BATCH - 1);
  uint32_t kt0, kt1;
  tf2x32(0u, 1234u, 0u, (uint32_t)t, kt0, kt1);
  uint32_t r0 = rbits32(kt0, kt1, (uint32_t)(2 * b));
  uint32_t r1 = rbits32(kt0, kt1, (uint32_t)(2 * b + 1));
  g[idx] = make_float2(gumb_from_bits(r0), gumb_from_bits(r1));
}

// ------ [WhT ; WdT ; zeros] (208 rows x 64) -> 3-term truncated-bf16 ------
__global__ void split_awt(const float* __restrict__ Wh, const float* __restrict__ Wd,
                          ushort* __restrict__ w0, ushort* __restrict__ w1,
                          ushort* __restrict__ w2) {
  int idx = blockIdx.x * 256 + threadIdx.x;   // 0..13311 = col*64 + j
  if (idx >= 208 * 64) return;
  int col = idx >> 6;
  int j   = idx & 63;
  float w;
  if (col < 192)      w = Wh[j * 192 + col];
  else if (col < 194) w = Wd[j * 2 + (col - 192)];
  else                w = 0.0f;
  uint32_t u0 = __float_as_uint(w) & 0xffff0000u;
  float f0 = __uint_as_float(u0);
  float r1 = w - f0;
  uint32_t u1 = __float_as_uint(r1) & 0xffff0000u;
  float f1 = __uint_as_float(u1);
  float r2 = r1 - f1;
  uint32_t u2 = __float_as_uint(r2) & 0xffff0000u;
  w0[idx] = (ushort)(u0 >> 16);
  w1[idx] = (ushort)(u1 >> 16);
  w2[idx] = (ushort)(u2 >> 16);
}

// XLA's logistic_expander form: 0.5 + 0.5*tanh(0.5*x)
__device__ __forceinline__ float sigmoid_xla(float x) {
  return 0.5f + 0.5f * tanhf(0.5f * x);
}

#define MF(A_, B_, C_) __builtin_amdgcn_mfma_f32_16x16x32_bf16((A_), (B_), (C_), 0, 0, 0)
#define F4(v_, r_) (((const float*)&(v_))[r_])

// ============ MFMA kernel v7: 6-product split + issue reorder =============
// vs R13: (1) unit tiles drop the 3 highest-order split products
// (A1B2, A2B1, A2B2; relative <= 2^-24) -> 36+12 MFMA/wave-step, matching
// the logits tile's existing 6-product chain; (2) unit-tile MFMAs are
// issued BEFORE the decision's exp/log VALU chain so the MFMA pipe stays
// fed during the serial decision (they don't depend on it; only the gate
// Wi-select does).  Everything else identical to R13.
__global__ __launch_bounds__(256, 2)
void rnn_mfma7(const float* __restrict__ Wi, const float* __restrict__ bb,
               const float* __restrict__ bd,
               const ushort* __restrict__ w0p, const ushort* __restrict__ w1p,
               const ushort* __restrict__ w2p, const float2* __restrict__ g,
               float* __restrict__ out_s, float* __restrict__ out_lp) {
  __shared__ __align__(16) ushort bsp[2][3072];   // h splits, B-frag layout
  __shared__ __align__(16) float c0zr[128];
  __shared__ __align__(16) float bh0a[64], bh1a[64];
  __shared__ __align__(16) float cw0[192], cw1[192];

  const int tid = threadIdx.x;
  const int l = tid & 63, s = l & 15, hi = l >> 4;
  const int w = tid >> 6;
  const int base = blockIdx.x * 16;

  if (tid < 64) {
    c0zr[tid] = bb[tid] + bb[192 + tid];
    c0zr[tid + 64] = bb[tid + 64] + bb[256 + tid];
    bh0a[tid] = bb[128 + tid];
    bh1a[tid] = bb[320 + tid];
    cw0[tid] = Wi[tid]; cw0[tid + 64] = Wi[tid + 64]; cw0[tid + 128] = Wi[tid + 128];
    cw1[tid] = Wi[192 + tid]; cw1[tid + 64] = Wi[256 + tid]; cw1[tid + 128] = Wi[320 + tid];
  }
  for (int k = tid; k < 1536; k += 256) ((uint*)bsp[0])[k] = 0u;  // h(-1)=0
  __syncthreads();

  // ---- A fragments: unit tiles {w,4+w,8+w} + logits tile 12, 3 splits ----
  v8s A0[3][2], A1[3][2], A2[3][2];
#pragma unroll
  for (int i3 = 0; i3 < 3; ++i3) {
    const int tile = w + 4 * i3;
#pragma unroll
    for (int kc = 0; kc < 2; ++kc) {
      const int off = (16 * tile + s) * 64 + 32 * kc + 8 * hi;
      A0[i3][kc] = *reinterpret_cast<const v8s*>(w0p + off);
      A1[i3][kc] = *reinterpret_cast<const v8s*>(w1p + off);
      A2[i3][kc] = *reinterpret_cast<const v8s*>(w2p + off);
    }
  }
  v8s L0[2], L1[2], L2[2];
#pragma unroll
  for (int kc = 0; kc < 2; ++kc) {
    const int off = (192 + s) * 64 + 32 * kc + 8 * hi;   // tile 12
    L0[kc] = *reinterpret_cast<const v8s*>(w0p + off);
    L1[kc] = *reinterpret_cast<const v8s*>(w1p + off);
    L2[kc] = *reinterpret_cast<const v8s*>(w2p + off);
  }

  const float bd0 = bd[0], bd1 = bd[1];
  const int u0i = 16 * w + 4 * hi;        // this wave's gate-unit group
  const float4 czv  = *reinterpret_cast<const float4*>(&c0zr[u0i]);
  const float4 crv  = *reinterpret_cast<const float4*>(&c0zr[64 + u0i]);
  const float4 bh0v = *reinterpret_cast<const float4*>(&bh0a[u0i]);
  const float4 bh1v = *reinterpret_cast<const float4*>(&bh1a[u0i]);
  const float4 wz0  = *reinterpret_cast<const float4*>(&cw0[u0i]);
  const float4 wz1  = *reinterpret_cast<const float4*>(&cw1[u0i]);
  const float4 wr0  = *reinterpret_cast<const float4*>(&cw0[64 + u0i]);
  const float4 wr1  = *reinterpret_cast<const float4*>(&cw1[64 + u0i]);
  const float4 wh0  = *reinterpret_cast<const float4*>(&cw0[128 + u0i]);
  const float4 wh1  = *reinterpret_cast<const float4*>(&cw1[128 + u0i]);

  const int kcw = w >> 1;
  const int hgw = (2 * w + (hi >> 1)) & 3;
  const int i0  = (hi & 1) * 4;

  float hreg[4] = {0.0f, 0.0f, 0.0f, 0.0f};
  float lp = 0.0f;
  float2 gcur = make_float2(0.0f, 0.0f), gnext = make_float2(0.0f, 0.0f);
  int p = 0;

  for (int t = 0; t <= NSITES; ++t) {
    if (t < NSITES && hi == 0) gnext = g[t * BATCH + base + s];

    // ---- B fragments of h(t-1) from LDS ----
    const ushort* rb = bsp[p] + hi * 128 + s * 8;
    v8s B0[2], B1[2], B2[2];
#pragma unroll
    for (int kc = 0; kc < 2; ++kc) {
      B0[kc] = *reinterpret_cast<const v8s*>(rb + kc * 512);
      B1[kc] = *reinterpret_cast<const v8s*>(rb + 1024 + kc * 512);
      B2[kc] = *reinterpret_cast<const v8s*>(rb + 2048 + kc * 512);
    }

    // ---- logits tile (6 products, low -> high) ----
    v4f al = {0.0f, 0.0f, 0.0f, 0.0f};
#pragma unroll
    for (int kc = 0; kc < 2; ++kc) al = MF(L1[kc], B1[kc], al);
#pragma unroll
    for (int kc = 0; kc < 2; ++kc) al = MF(L2[kc], B0[kc], al);
#pragma unroll
    for (int kc = 0; kc < 2; ++kc) al = MF(L0[kc], B2[kc], al);
#pragma unroll
    for (int kc = 0; kc < 2; ++kc) al = MF(L1[kc], B0[kc], al);
#pragma unroll
    for (int kc = 0; kc < 2; ++kc) al = MF(L0[kc], B1[kc], al);
#pragma unroll
    for (int kc = 0; kc < 2; ++kc) al = MF(L0[kc], B0[kc], al);

    // ---- unit tiles issued BEFORE the decision VALU chain (independent) --
    v4f acc[3];
    if (t < NSITES) {
#pragma unroll
      for (int i3 = 0; i3 < 3; ++i3) {
        v4f a = {0.0f, 0.0f, 0.0f, 0.0f};
#pragma unroll
        for (int kc = 0; kc < 2; ++kc) a = MF(A2[i3][kc], B0[kc], a);
#pragma unroll
        for (int kc = 0; kc < 2; ++kc) a = MF(A0[i3][kc], B2[kc], a);
#pragma unroll
        for (int kc = 0; kc < 2; ++kc) a = MF(A1[i3][kc], B1[kc], a);
#pragma unroll
        for (int kc = 0; kc < 2; ++kc) a = MF(A1[i3][kc], B0[kc], a);
#pragma unroll
        for (int kc = 0; kc < 2; ++kc) a = MF(A0[i3][kc], B1[kc], a);
#pragma unroll
        for (int kc = 0; kc < 2; ++kc) a = MF(A0[i3][kc], B0[kc], a);
        acc[i3] = a;
      }
    }

    // ---- decision(t-1): lanes 0-15 hold l0 (row0) / l1 (row1) ----
    int scd = 0;
    if (t > 0) {
      const float l0 = al[0] + bd0, l1 = al[1] + bd1;
      const float mmax = fmaxf(l0, l1);
      const float sh0 = l0 - mmax, sh1 = l1 - mmax;
      const float lse = logf(expf(sh0) + expf(sh1));
      scd = ((l1 + gcur.y) > (l0 + gcur.x)) ? 1 : 0;
      lp += (scd ? sh1 : sh0) - lse;
      if (tid < 16) out_s[(size_t)(base + s) * NSITES + (t - 1)] = (float)scd;
    }

    if (t < NSITES) {
      const int scb = __shfl(scd, s, 64);   // decision(t-1), all lanes

      // ---- gates for this wave's 16 units (identical math) ----
      float selz[4], selr[4], selh[4];
      if (t == 0) {
#pragma unroll
        for (int r = 0; r < 4; ++r) { selz[r] = 0.0f; selr[r] = 0.0f; selh[r] = 0.0f; }
      } else {
#pragma unroll
        for (int r = 0; r < 4; ++r) {
          selz[r] = scb ? F4(wz1, r) : F4(wz0, r);
          selr[r] = scb ? F4(wr1, r) : F4(wr0, r);
          selh[r] = scb ? F4(wh1, r) : F4(wh0, r);
        }
      }

      uint sp0[4], sp1[4], sp2[4];
#pragma unroll
      for (int r = 0; r < 4; ++r) {
        const float zin = acc[0][r] + F4(czv, r) + selz[r];
        const float rin = acc[1][r] + F4(crv, r) + selr[r];
        const float rhv = acc[2][r] + F4(bh1v, r);
        const float xhv = F4(bh0v, r) + selh[r];
        const float zg = sigmoid_xla(zin);
        const float rg = sigmoid_xla(rin);
        const float hg = tanhf(xhv + rg * rhv);
        const float hn = zg * hreg[r] + (1.0f - zg) * hg;
        hreg[r] = hn;
        const uint u0 = __float_as_uint(hn) & 0xffff0000u;
        const float f0 = __uint_as_float(u0);
        const float r1f = hn - f0;
        const uint u1 = __float_as_uint(r1f) & 0xffff0000u;
        const float f1 = __uint_as_float(u1);
        const float r2f = r1f - f1;
        const uint u2 = __float_as_uint(r2f) & 0xffff0000u;
        sp0[r] = u0 >> 16; sp1[r] = u1 >> 16; sp2[r] = u2 >> 16;
      }
      ushort* wb = bsp[p ^ 1] + kcw * 512 + hgw * 128 + s * 8 + i0;
      {
        uint2 q;
        q.x = sp0[0] | (sp0[1] << 16); q.y = sp0[2] | (sp0[3] << 16);
        *reinterpret_cast<uint2*>(wb) = q;
        q.x = sp1[0] | (sp1[1] << 16); q.y = sp1[2] | (sp1[3] << 16);
        *reinterpret_cast<uint2*>(wb + 1024) = q;
        q.x = sp2[0] | (sp2[1] << 16); q.y = sp2[2] | (sp2[3] << 16);
        *reinterpret_cast<uint2*>(wb + 2048) = q;
      }
    }

    __syncthreads();   // h(t) splits visible; reads of bsp[p] complete
    p ^= 1;
    gcur = gnext;
  }

  if (tid < 16) out_lp[base + s] = 0.5f * lp;
}

// ---------------- fallback (ws too small): proven bit-exact path ----------
__global__ __launch_bounds__(64)
void rnn_plain(const float* __restrict__ Wi, const float* __restrict__ Wh,
               const float* __restrict__ bb, const float* __restrict__ Wd,
               const float* __restrict__ bd,
               float* __restrict__ out_s, float* __restrict__ out_lp) {
  const int lane = threadIdx.x;
  const int b = blockIdx.x;

  float wz[NHID], wr[NHID], wh[NHID];
#pragma unroll
  for (int j = 0; j < NHID; ++j) {
    wz[j] = Wh[j * 192 + lane];
    wr[j] = Wh[j * 192 + 64 + lane];
    wh[j] = Wh[j * 192 + 128 + lane];
  }
  const float b1z = bb[192 + lane];
  const float b1r = bb[192 + 64 + lane];
  const float b1h = bb[192 + 128 + lane];
  const float m0z = bb[lane], m0r = bb[64 + lane], m0h = bb[128 + lane];
  const float m1z = Wi[lane] + m0z, m1r = Wi[64 + lane] + m0r, m1h = Wi[128 + lane] + m0h;
  const float m2z = Wi[192 + lane] + m0z, m2r = Wi[192 + 64 + lane] + m0r,
              m2h = Wi[192 + 128 + lane] + m0h;
  const float wd0 = Wd[lane * 2 + 0], wd1 = Wd[lane * 2 + 1];
  const float bd0 = bd[0], bd1 = bd[1];

  float h = 0.0f, lpsum = 0.0f;
  float xz = m0z, xr = m0r, xh = m0h;

  for (int t = 0; t < NSITES; ++t) {
    uint32_t kt0, kt1;
    tf2x32(0u, 1234u, 0u, (uint32_t)t, kt0, kt1);
    const float g0 = gumb_from_bits(rbits32(kt0, kt1, (uint32_t)(2 * b)));
    const float g1 = gumb_from_bits(rbits32(kt0, kt1, (uint32_t)(2 * b + 1)));

    float az = 0.0f, ar = 0.0f, ah = 0.0f;
#pragma unroll
    for (int j = 0; j < NHID; ++j) {
      const float hj = __int_as_float(__builtin_amdgcn_readlane(__float_as_int(h), j));
      az = fmaf(hj, wz[j], az);
      ar = fmaf(hj, wr[j], ar);
      ah = fmaf(hj, wh[j], ah);
    }
    const float rz = az + b1z, rr = ar + b1r, rh = ah + b1h;
    const float zg = sigmoid_xla(xz + rz);
    const float rg = sigmoid_xla(xr + rr);
    const float hg = tanhf(xh + rg * rh);
    h = zg * h + (1.0f - zg) * hg;

    float p0 = h * wd0, p1 = h * wd1;
#pragma unroll
    for (int off = 32; off > 0; off >>= 1) {
      p0 += __shfl_xor(p0, off, 64);
      p1 += __shfl_xor(p1, off, 64);
    }
    const float l0 = p0 + bd0, l1 = p1 + bd1;
    const float mmax = fmaxf(l0, l1);
    const float sh0 = l0 - mmax, sh1 = l1 - mmax;
    const float lse = logf(expf(sh0) + expf(sh1));
    const int si = ((l1 + g1) > (l0 + g0)) ? 1 : 0;
    lpsum += (si ? sh1 : sh0) - lse;
    if (lane == 0) out_s[(size_t)b * NSITES + t] = (float)si;
    xz = si ? m2z : m1z;
    xr = si ? m2r : m1r;
    xh = si ? m2h : m1h;
  }

  if (lane == 0) out_lp[b] = 0.5f * lpsum;
}

extern "C" void kernel_launch(void* const* d_in, const int* in_sizes, int n_in,
                              void* d_out, int out_size, void* d_ws, size_t ws_size,
                              hipStream_t stream) {
  const float* Wi = (const float*)d_in[1];
  const float* Wh = (const float*)d_in[2];
  const float* bb = (const float*)d_in[3];
  const float* Wd = (const float*)d_in[4];
  const float* bd = (const float*)d_in[5];

  float* out    = (float*)d_out;
  float* out_s  = out;                           // [8192][256]
  float* out_lp = out + (size_t)BATCH * NSITES;  // [8192]

  const size_t gbytes = (size_t)NSITES * BATCH * sizeof(float2);  // 16 MiB
  const size_t wb = (size_t)208 * 64 * sizeof(ushort);            // 26 KiB

  if (ws_size >= gbytes + 3 * wb) {
    float2* g  = (float2*)d_ws;
    ushort* w0 = (ushort*)((char*)d_ws + gbytes);
    ushort* w1 = w0 + 208 * 64;
    ushort* w2 = w1 + 208 * 64;
    gumbel_precompute<<<(NSITES * BATCH) / 256, 256, 0, stream>>>(g);
    split_awt<<<(208 * 64 + 255) / 256, 256, 0, stream>>>(Wh, Wd, w0, w1, w2);
    rnn_mfma7<<<BATCH / 16, 256, 0, stream>>>(Wi, bb, bd, w0, w1, w2, g, out_s, out_lp);
  } else {
    rnn_plain<<<BATCH, 64, 0, stream>>>(Wi, Wh, bb, Wd, bd, out_s, out_lp);
  }
}

// Round 15
// 402.900 us; speedup vs baseline: 1.5955x; 1.0460x over previous
//
#include <hip/hip_runtime.h>
#include <stdint.h>

#define NSITES 256
#define NHID   64
#define BATCH  8192

typedef float v4f __attribute__((ext_vector_type(4)));
typedef short v8s __attribute__((ext_vector_type(8)));

// ---------------- threefry2x32 (exact JAX semantics) ----------------
__device__ __forceinline__ uint32_t rotl32(uint32_t v, int d) {
  return (v << d) | (v >> (32 - d));
}

__device__ __forceinline__ void tf2x32(uint32_t k0, uint32_t k1,
                                       uint32_t x0, uint32_t x1,
                                       uint32_t& o0, uint32_t& o1) {
  uint32_t ks2 = k0 ^ k1 ^ 0x1BD11BDAu;
  x0 += k0; x1 += k1;
#define TFR4(a,b,c,d) \
  x0 += x1; x1 = rotl32(x1,a); x1 ^= x0; \
  x0 += x1; x1 = rotl32(x1,b); x1 ^= x0; \
  x0 += x1; x1 = rotl32(x1,c); x1 ^= x0; \
  x0 += x1; x1 = rotl32(x1,d); x1 ^= x0;
  TFR4(13,15,26,6)   x0 += k1;  x1 += ks2 + 1u;
  TFR4(17,29,16,24)  x0 += ks2; x1 += k0  + 2u;
  TFR4(13,15,26,6)   x0 += k0;  x1 += k1  + 3u;
  TFR4(17,29,16,24)  x0 += k1;  x1 += ks2 + 4u;
  TFR4(13,15,26,6)   x0 += ks2; x1 += k0  + 5u;
#undef TFR4
  o0 = x0; o1 = x1;
}

__device__ __forceinline__ float gumb_from_bits(uint32_t bits) {
  float f = __uint_as_float((bits >> 9) | 0x3f800000u) - 1.0f;
  float u = (f == 0.0f) ? 1.17549435e-38f : f;
  return -logf(-logf(u));
}

__device__ __forceinline__ uint32_t rbits32(uint32_t k0, uint32_t k1, uint32_t e) {
  uint32_t a, b;
  tf2x32(k0, k1, 0u, e, a, b);
  return a ^ b;
}

// ------ [WhT ; Wd-replicated ; zeros] (208 x 64) -> 3-term bf16 split ------
// rows 0-191: WhT[gate*64+unit][j].  rows 192-207 (logits tile): row
// 192+4k+0 = Wd col0, 192+4k+1 = Wd col1, else 0 -> every lane's D regs
// 0/1 hold l0/l1 (bitwise-identical MFMA rows) -> all-lane local decision.
__global__ void split_awt(const float* __restrict__ Wh, const float* __restrict__ Wd,
                          ushort* __restrict__ w0, ushort* __restrict__ w1,
                          ushort* __restrict__ w2) {
  int idx = blockIdx.x * 256 + threadIdx.x;   // 0..13311 = col*64 + j
  if (idx >= 208 * 64) return;
  int col = idx >> 6;
  int j   = idx & 63;
  float w;
  if (col < 192) {
    w = Wh[j * 192 + col];
  } else {
    const int which = (col - 192) & 3;
    w = (which == 0) ? Wd[j * 2] : (which == 1) ? Wd[j * 2 + 1] : 0.0f;
  }
  uint32_t u0 = __float_as_uint(w) & 0xffff0000u;
  float f0 = __uint_as_float(u0);
  float r1 = w - f0;
  uint32_t u1 = __float_as_uint(r1) & 0xffff0000u;
  float f1 = __uint_as_float(u1);
  float r2 = r1 - f1;
  uint32_t u2 = __float_as_uint(r2) & 0xffff0000u;
  w0[idx] = (ushort)(u0 >> 16);
  w1[idx] = (ushort)(u1 >> 16);
  w2[idx] = (ushort)(u2 >> 16);
}

// XLA's logistic_expander form: 0.5 + 0.5*tanh(0.5*x)
__device__ __forceinline__ float sigmoid_xla(float x) {
  return 0.5f + 0.5f * tanhf(0.5f * x);
}

#define MF(A_, B_, C_) __builtin_amdgcn_mfma_f32_16x16x32_bf16((A_), (B_), (C_), 0, 0, 0)
#define F4(v_, r_) (((const float*)&(v_))[r_])

// ============ MFMA kernel v9: no shfl, in-block gumbels ===================
// vs R14: (1) Wd-replicated logits rows -> every lane holds l0/l1 locally,
// decision needs NO __shfl (DS op off the critical path); (2) gumbels are
// generated once per block into LDS (thread t computes step t's 16 pairs,
// same tf2x32 bits as the old precompute kernel) -> no global gumbel
// stream, no separate kernel.  All FP ops bit-identical to R14.
__global__ __launch_bounds__(256, 2)
void rnn_mfma9(const float* __restrict__ Wi, const float* __restrict__ bb,
               const float* __restrict__ bd,
               const ushort* __restrict__ w0p, const ushort* __restrict__ w1p,
               const ushort* __restrict__ w2p,
               float* __restrict__ out_s, float* __restrict__ out_lp) {
  __shared__ __align__(16) ushort bsp[2][3072];   // h splits, B-frag layout
  __shared__ __align__(16) float2 gl[NSITES * 16];  // gumbels [t][s], 32 KiB
  __shared__ __align__(16) float c0zr[128];
  __shared__ __align__(16) float bh0a[64], bh1a[64];
  __shared__ __align__(16) float cw0[192], cw1[192];

  const int tid = threadIdx.x;
  const int l = tid & 63, s = l & 15, hi = l >> 4;
  const int w = tid >> 6;
  const int base = blockIdx.x * 16;

  if (tid < 64) {
    c0zr[tid] = bb[tid] + bb[192 + tid];
    c0zr[tid + 64] = bb[tid + 64] + bb[256 + tid];
    bh0a[tid] = bb[128 + tid];
    bh1a[tid] = bb[320 + tid];
    cw0[tid] = Wi[tid]; cw0[tid + 64] = Wi[tid + 64]; cw0[tid + 128] = Wi[tid + 128];
    cw1[tid] = Wi[192 + tid]; cw1[tid + 64] = Wi[256 + tid]; cw1[tid + 128] = Wi[320 + tid];
  }
  for (int k = tid; k < 1536; k += 256) ((uint*)bsp[0])[k] = 0u;  // h(-1)=0

  // ---- gumbel prologue: thread tid = step t, its 16 samples ----
  {
    uint32_t kt0, kt1;
    tf2x32(0u, 1234u, 0u, (uint32_t)tid, kt0, kt1);
    for (int k = 0; k < 16; ++k) {
      const int bidx = base + k;
      const float g0 = gumb_from_bits(rbits32(kt0, kt1, (uint32_t)(2 * bidx)));
      const float g1 = gumb_from_bits(rbits32(kt0, kt1, (uint32_t)(2 * bidx + 1)));
      gl[tid * 16 + k] = make_float2(g0, g1);
    }
  }
  __syncthreads();

  // ---- A fragments: unit tiles {w,4+w,8+w} + logits tile 12, 3 splits ----
  v8s A0[3][2], A1[3][2], A2[3][2];
#pragma unroll
  for (int i3 = 0; i3 < 3; ++i3) {
    const int tile = w + 4 * i3;
#pragma unroll
    for (int kc = 0; kc < 2; ++kc) {
      const int off = (16 * tile + s) * 64 + 32 * kc + 8 * hi;
      A0[i3][kc] = *reinterpret_cast<const v8s*>(w0p + off);
      A1[i3][kc] = *reinterpret_cast<const v8s*>(w1p + off);
      A2[i3][kc] = *reinterpret_cast<const v8s*>(w2p + off);
    }
  }
  v8s L0[2], L1[2], L2[2];
#pragma unroll
  for (int kc = 0; kc < 2; ++kc) {
    const int off = (192 + s) * 64 + 32 * kc + 8 * hi;   // tile 12
    L0[kc] = *reinterpret_cast<const v8s*>(w0p + off);
    L1[kc] = *reinterpret_cast<const v8s*>(w1p + off);
    L2[kc] = *reinterpret_cast<const v8s*>(w2p + off);
  }

  const float bd0 = bd[0], bd1 = bd[1];
  const int u0i = 16 * w + 4 * hi;        // this wave's gate-unit group
  const float4 czv  = *reinterpret_cast<const float4*>(&c0zr[u0i]);
  const float4 crv  = *reinterpret_cast<const float4*>(&c0zr[64 + u0i]);
  const float4 bh0v = *reinterpret_cast<const float4*>(&bh0a[u0i]);
  const float4 bh1v = *reinterpret_cast<const float4*>(&bh1a[u0i]);
  const float4 wz0  = *reinterpret_cast<const float4*>(&cw0[u0i]);
  const float4 wz1  = *reinterpret_cast<const float4*>(&cw1[u0i]);
  const float4 wr0  = *reinterpret_cast<const float4*>(&cw0[64 + u0i]);
  const float4 wr1  = *reinterpret_cast<const float4*>(&cw1[64 + u0i]);
  const float4 wh0  = *reinterpret_cast<const float4*>(&cw0[128 + u0i]);
  const float4 wh1  = *reinterpret_cast<const float4*>(&cw1[128 + u0i]);

  const int kcw = w >> 1;
  const int hgw = (2 * w + (hi >> 1)) & 3;
  const int i0  = (hi & 1) * 4;

  float hreg[4] = {0.0f, 0.0f, 0.0f, 0.0f};
  float lp = 0.0f;
  int p = 0;

  for (int t = 0; t <= NSITES; ++t) {
    // ---- B fragments of h(t-1) from LDS ----
    const ushort* rb = bsp[p] + hi * 128 + s * 8;
    v8s B0[2], B1[2], B2[2];
#pragma unroll
    for (int kc = 0; kc < 2; ++kc) {
      B0[kc] = *reinterpret_cast<const v8s*>(rb + kc * 512);
      B1[kc] = *reinterpret_cast<const v8s*>(rb + 1024 + kc * 512);
      B2[kc] = *reinterpret_cast<const v8s*>(rb + 2048 + kc * 512);
    }

    // ---- logits tile (6 products, low -> high) ----
    v4f al = {0.0f, 0.0f, 0.0f, 0.0f};
#pragma unroll
    for (int kc = 0; kc < 2; ++kc) al = MF(L1[kc], B1[kc], al);
#pragma unroll
    for (int kc = 0; kc < 2; ++kc) al = MF(L2[kc], B0[kc], al);
#pragma unroll
    for (int kc = 0; kc < 2; ++kc) al = MF(L0[kc], B2[kc], al);
#pragma unroll
    for (int kc = 0; kc < 2; ++kc) al = MF(L1[kc], B0[kc], al);
#pragma unroll
    for (int kc = 0; kc < 2; ++kc) al = MF(L0[kc], B1[kc], al);
#pragma unroll
    for (int kc = 0; kc < 2; ++kc) al = MF(L0[kc], B0[kc], al);

    // ---- unit tiles issued BEFORE the decision VALU chain (independent) --
    v4f acc[3];
    if (t < NSITES) {
#pragma unroll
      for (int i3 = 0; i3 < 3; ++i3) {
        v4f a = {0.0f, 0.0f, 0.0f, 0.0f};
#pragma unroll
        for (int kc = 0; kc < 2; ++kc) a = MF(A2[i3][kc], B0[kc], a);
#pragma unroll
        for (int kc = 0; kc < 2; ++kc) a = MF(A0[i3][kc], B2[kc], a);
#pragma unroll
        for (int kc = 0; kc < 2; ++kc) a = MF(A1[i3][kc], B1[kc], a);
#pragma unroll
        for (int kc = 0; kc < 2; ++kc) a = MF(A1[i3][kc], B0[kc], a);
#pragma unroll
        for (int kc = 0; kc < 2; ++kc) a = MF(A0[i3][kc], B1[kc], a);
#pragma unroll
        for (int kc = 0; kc < 2; ++kc) a = MF(A0[i3][kc], B0[kc], a);
        acc[i3] = a;
      }
    }

    // ---- decision(t-1): every lane holds l0/l1 (Wd-replicated rows) ----
    int scd = 0;
    if (t > 0) {
      const float2 gc = gl[(t - 1) * 16 + s];
      const float l0 = al[0] + bd0, l1 = al[1] + bd1;
      const float mmax = fmaxf(l0, l1);
      const float sh0 = l0 - mmax, sh1 = l1 - mmax;
      const float lse = logf(expf(sh0) + expf(sh1));
      scd = ((l1 + gc.y) > (l0 + gc.x)) ? 1 : 0;
      lp += (scd ? sh1 : sh0) - lse;
      if (tid < 16) out_s[(size_t)(base + s) * NSITES + (t - 1)] = (float)scd;
    }

    if (t < NSITES) {
      // ---- gates for this wave's 16 units (identical math) ----
      float selz[4], selr[4], selh[4];
      if (t == 0) {
#pragma unroll
        for (int r = 0; r < 4; ++r) { selz[r] = 0.0f; selr[r] = 0.0f; selh[r] = 0.0f; }
      } else {
#pragma unroll
        for (int r = 0; r < 4; ++r) {
          selz[r] = scd ? F4(wz1, r) : F4(wz0, r);
          selr[r] = scd ? F4(wr1, r) : F4(wr0, r);
          selh[r] = scd ? F4(wh1, r) : F4(wh0, r);
        }
      }

      uint sp0[4], sp1[4], sp2[4];
#pragma unroll
      for (int r = 0; r < 4; ++r) {
        const float zin = acc[0][r] + F4(czv, r) + selz[r];
        const float rin = acc[1][r] + F4(crv, r) + selr[r];
        const float rhv = acc[2][r] + F4(bh1v, r);
        const float xhv = F4(bh0v, r) + selh[r];
        const float zg = sigmoid_xla(zin);
        const float rg = sigmoid_xla(rin);
        const float hg = tanhf(xhv + rg * rhv);
        const float hn = zg * hreg[r] + (1.0f - zg) * hg;
        hreg[r] = hn;
        const uint u0 = __float_as_uint(hn) & 0xffff0000u;
        const float f0 = __uint_as_float(u0);
        const float r1f = hn - f0;
        const uint u1 = __float_as_uint(r1f) & 0xffff0000u;
        const float f1 = __uint_as_float(u1);
        const float r2f = r1f - f1;
        const uint u2 = __float_as_uint(r2f) & 0xffff0000u;
        sp0[r] = u0 >> 16; sp1[r] = u1 >> 16; sp2[r] = u2 >> 16;
      }
      ushort* wb = bsp[p ^ 1] + kcw * 512 + hgw * 128 + s * 8 + i0;
      {
        uint2 q;
        q.x = sp0[0] | (sp0[1] << 16); q.y = sp0[2] | (sp0[3] << 16);
        *reinterpret_cast<uint2*>(wb) = q;
        q.x = sp1[0] | (sp1[1] << 16); q.y = sp1[2] | (sp1[3] << 16);
        *reinterpret_cast<uint2*>(wb + 1024) = q;
        q.x = sp2[0] | (sp2[1] << 16); q.y = sp2[2] | (sp2[3] << 16);
        *reinterpret_cast<uint2*>(wb + 2048) = q;
      }
    }

    __syncthreads();   // h(t) splits visible; reads of bsp[p] complete
    p ^= 1;
  }

  if (tid < 16) out_lp[base + s] = 0.5f * lp;
}

// ---------------- fallback (ws too small): proven bit-exact path ----------
__global__ __launch_bounds__(64)
void rnn_plain(const float* __restrict__ Wi, const float* __restrict__ Wh,
               const float* __restrict__ bb, const float* __restrict__ Wd,
               const float* __restrict__ bd,
               float* __restrict__ out_s, float* __restrict__ out_lp) {
  const int lane = threadIdx.x;
  const int b = blockIdx.x;

  float wz[NHID], wr[NHID], wh[NHID];
#pragma unroll
  for (int j = 0; j < NHID; ++j) {
    wz[j] = Wh[j * 192 + lane];
    wr[j] = Wh[j * 192 + 64 + lane];
    wh[j] = Wh[j * 192 + 128 + lane];
  }
  const float b1z = bb[192 + lane];
  const float b1r = bb[192 + 64 + lane];
  const float b1h = bb[192 + 128 + lane];
  const float m0z = bb[lane], m0r = bb[64 + lane], m0h = bb[128 + lane];
  const float m1z = Wi[lane] + m0z, m1r = Wi[64 + lane] + m0r, m1h = Wi[128 + lane] + m0h;
  const float m2z = Wi[192 + lane] + m0z, m2r = Wi[192 + 64 + lane] + m0r,
              m2h = Wi[192 + 128 + lane] + m0h;
  const float wd0 = Wd[lane * 2 + 0], wd1 = Wd[lane * 2 + 1];
  const float bd0 = bd[0], bd1 = bd[1];

  float h = 0.0f, lpsum = 0.0f;
  float xz = m0z, xr = m0r, xh = m0h;

  for (int t = 0; t < NSITES; ++t) {
    uint32_t kt0, kt1;
    tf2x32(0u, 1234u, 0u, (uint32_t)t, kt0, kt1);
    const float g0 = gumb_from_bits(rbits32(kt0, kt1, (uint32_t)(2 * b)));
    const float g1 = gumb_from_bits(rbits32(kt0, kt1, (uint32_t)(2 * b + 1)));

    float az = 0.0f, ar = 0.0f, ah = 0.0f;
#pragma unroll
    for (int j = 0; j < NHID; ++j) {
      const float hj = __int_as_float(__builtin_amdgcn_readlane(__float_as_int(h), j));
      az = fmaf(hj, wz[j], az);
      ar = fmaf(hj, wr[j], ar);
      ah = fmaf(hj, wh[j], ah);
    }
    const float rz = az + b1z, rr = ar + b1r, rh = ah + b1h;
    const float zg = sigmoid_xla(xz + rz);
    const float rg = sigmoid_xla(xr + rr);
    const float hg = tanhf(xh + rg * rh);
    h = zg * h + (1.0f - zg) * hg;

    float p0 = h * wd0, p1 = h * wd1;
#pragma unroll
    for (int off = 32; off > 0; off >>= 1) {
      p0 += __shfl_xor(p0, off, 64);
      p1 += __shfl_xor(p1, off, 64);
    }
    const float l0 = p0 + bd0, l1 = p1 + bd1;
    const float mmax = fmaxf(l0, l1);
    const float sh0 = l0 - mmax, sh1 = l1 - mmax;
    const float lse = logf(expf(sh0) + expf(sh1));
    const int si = ((l1 + g1) > (l0 + g0)) ? 1 : 0;
    lpsum += (si ? sh1 : sh0) - lse;
    if (lane == 0) out_s[(size_t)b * NSITES + t] = (float)si;
    xz = si ? m2z : m1z;
    xr = si ? m2r : m1r;
    xh = si ? m2h : m1h;
  }

  if (lane == 0) out_lp[b] = 0.5f * lpsum;
}

extern "C" void kernel_launch(void* const* d_in, const int* in_sizes, int n_in,
                              void* d_out, int out_size, void* d_ws, size_t ws_size,
                              hipStream_t stream) {
  const float* Wi = (const float*)d_in[1];
  const float* Wh = (const float*)d_in[2];
  const float* bb = (const float*)d_in[3];
  const float* Wd = (const float*)d_in[4];
  const float* bd = (const float*)d_in[5];

  float* out    = (float*)d_out;
  float* out_s  = out;                           // [8192][256]
  float* out_lp = out + (size_t)BATCH * NSITES;  // [8192]

  const size_t wb = (size_t)208 * 64 * sizeof(ushort);   // 26 KiB per split

  if (ws_size >= 3 * wb) {
    ushort* w0 = (ushort*)d_ws;
    ushort* w1 = w0 + 208 * 64;
    ushort* w2 = w1 + 208 * 64;
    split_awt<<<(208 * 64 + 255) / 256, 256, 0, stream>>>(Wh, Wd, w0, w1, w2);
    rnn_mfma9<<<BATCH / 16, 256, 0, stream>>>(Wi, bb, bd, w0, w1, w2, out_s, out_lp);
  } else {
    rnn_plain<<<BATCH, 64, 0, stream>>>(Wi, Wh, bb, Wd, bd, out_s, out_lp);
  }
}

// Round 16
// 395.211 us; speedup vs baseline: 1.6265x; 1.0195x over previous
//
#include <hip/hip_runtime.h>
#include <stdint.h>

#define NSITES 256
#define NHID   64
#define BATCH  8192

typedef float v4f __attribute__((ext_vector_type(4)));
typedef short v8s __attribute__((ext_vector_type(8)));

// ---------------- threefry2x32 (exact JAX semantics) ----------------
__device__ __forceinline__ uint32_t rotl32(uint32_t v, int d) {
  return (v << d) | (v >> (32 - d));
}

__device__ __forceinline__ void tf2x32(uint32_t k0, uint32_t k1,
                                       uint32_t x0, uint32_t x1,
                                       uint32_t& o0, uint32_t& o1) {
  uint32_t ks2 = k0 ^ k1 ^ 0x1BD11BDAu;
  x0 += k0; x1 += k1;
#define TFR4(a,b,c,d) \
  x0 += x1; x1 = rotl32(x1,a); x1 ^= x0; \
  x0 += x1; x1 = rotl32(x1,b); x1 ^= x0; \
  x0 += x1; x1 = rotl32(x1,c); x1 ^= x0; \
  x0 += x1; x1 = rotl32(x1,d); x1 ^= x0;
  TFR4(13,15,26,6)   x0 += k1;  x1 += ks2 + 1u;
  TFR4(17,29,16,24)  x0 += ks2; x1 += k0  + 2u;
  TFR4(13,15,26,6)   x0 += k0;  x1 += k1  + 3u;
  TFR4(17,29,16,24)  x0 += k1;  x1 += ks2 + 4u;
  TFR4(13,15,26,6)   x0 += ks2; x1 += k0  + 5u;
#undef TFR4
  o0 = x0; o1 = x1;
}

__device__ __forceinline__ float gumb_from_bits(uint32_t bits) {
  float f = __uint_as_float((bits >> 9) | 0x3f800000u) - 1.0f;
  float u = (f == 0.0f) ? 1.17549435e-38f : f;
  return -logf(-logf(u));
}

__device__ __forceinline__ uint32_t rbits32(uint32_t k0, uint32_t k1, uint32_t e) {
  uint32_t a, b;
  tf2x32(k0, k1, 0u, e, a, b);
  return a ^ b;
}

// ------ [WhT ; Wd-replicated ; zeros] (208 x 64) -> 3-term bf16 split ------
// rows 0-191: WhT[gate*64+unit][j].  rows 192-207 (logits tile): row
// 192+4k+0 = Wd col0, 192+4k+1 = Wd col1, else 0 -> every lane's D regs
// 0/1 hold l0/l1 (bitwise-identical MFMA rows) -> all-lane local decision.
__global__ void split_awt(const float* __restrict__ Wh, const float* __restrict__ Wd,
                          ushort* __restrict__ w0, ushort* __restrict__ w1,
                          ushort* __restrict__ w2) {
  int idx = blockIdx.x * 256 + threadIdx.x;   // 0..13311 = col*64 + j
  if (idx >= 208 * 64) return;
  int col = idx >> 6;
  int j   = idx & 63;
  float w;
  if (col < 192) {
    w = Wh[j * 192 + col];
  } else {
    const int which = (col - 192) & 3;
    w = (which == 0) ? Wd[j * 2] : (which == 1) ? Wd[j * 2 + 1] : 0.0f;
  }
  uint32_t u0 = __float_as_uint(w) & 0xffff0000u;
  float f0 = __uint_as_float(u0);
  float r1 = w - f0;
  uint32_t u1 = __float_as_uint(r1) & 0xffff0000u;
  float f1 = __uint_as_float(u1);
  float r2 = r1 - f1;
  uint32_t u2 = __float_as_uint(r2) & 0xffff0000u;
  w0[idx] = (ushort)(u0 >> 16);
  w1[idx] = (ushort)(u1 >> 16);
  w2[idx] = (ushort)(u2 >> 16);
}

// XLA's logistic_expander form: 0.5 + 0.5*tanh(0.5*x)
__device__ __forceinline__ float sigmoid_xla(float x) {
  return 0.5f + 0.5f * tanhf(0.5f * x);
}

#define MF(A_, B_, C_) __builtin_amdgcn_mfma_f32_16x16x32_bf16((A_), (B_), (C_), 0, 0, 0)
#define F4(v_, r_) (((const float*)&(v_))[r_])

// ============ MFMA kernel v10: critical-path reorder =====================
// vs R15 (bit-identical FP ops, different issue positions):
//  - gumbel LDS read hoisted to loop top (hides under B-frag reads);
//  - decision COMPARE (2 add + cmp) right after the logits chain -> gates
//    start without waiting on exp/log;
//  - lse/lp/out_s (the ~150-cyc exp->log chain) deferred past the LDS
//    writes, overlapping the barrier wait and next step's reads.
__global__ __launch_bounds__(256, 2)
void rnn_mfma10(const float* __restrict__ Wi, const float* __restrict__ bb,
                const float* __restrict__ bd,
                const ushort* __restrict__ w0p, const ushort* __restrict__ w1p,
                const ushort* __restrict__ w2p,
                float* __restrict__ out_s, float* __restrict__ out_lp) {
  __shared__ __align__(16) ushort bsp[2][3072];     // h splits, B-frag layout
  __shared__ __align__(16) float2 gl[NSITES * 16];  // gumbels [t][s], 32 KiB
  __shared__ __align__(16) float c0zr[128];
  __shared__ __align__(16) float bh0a[64], bh1a[64];
  __shared__ __align__(16) float cw0[192], cw1[192];

  const int tid = threadIdx.x;
  const int l = tid & 63, s = l & 15, hi = l >> 4;
  const int w = tid >> 6;
  const int base = blockIdx.x * 16;

  if (tid < 64) {
    c0zr[tid] = bb[tid] + bb[192 + tid];
    c0zr[tid + 64] = bb[tid + 64] + bb[256 + tid];
    bh0a[tid] = bb[128 + tid];
    bh1a[tid] = bb[320 + tid];
    cw0[tid] = Wi[tid]; cw0[tid + 64] = Wi[tid + 64]; cw0[tid + 128] = Wi[tid + 128];
    cw1[tid] = Wi[192 + tid]; cw1[tid + 64] = Wi[256 + tid]; cw1[tid + 128] = Wi[320 + tid];
  }
  for (int k = tid; k < 1536; k += 256) ((uint*)bsp[0])[k] = 0u;  // h(-1)=0

  // ---- gumbel prologue: thread tid = step t, its 16 samples ----
  {
    uint32_t kt0, kt1;
    tf2x32(0u, 1234u, 0u, (uint32_t)tid, kt0, kt1);
    for (int k = 0; k < 16; ++k) {
      const int bidx = base + k;
      const float g0 = gumb_from_bits(rbits32(kt0, kt1, (uint32_t)(2 * bidx)));
      const float g1 = gumb_from_bits(rbits32(kt0, kt1, (uint32_t)(2 * bidx + 1)));
      gl[tid * 16 + k] = make_float2(g0, g1);
    }
  }
  __syncthreads();

  // ---- A fragments: unit tiles {w,4+w,8+w} + logits tile 12, 3 splits ----
  v8s A0[3][2], A1[3][2], A2[3][2];
#pragma unroll
  for (int i3 = 0; i3 < 3; ++i3) {
    const int tile = w + 4 * i3;
#pragma unroll
    for (int kc = 0; kc < 2; ++kc) {
      const int off = (16 * tile + s) * 64 + 32 * kc + 8 * hi;
      A0[i3][kc] = *reinterpret_cast<const v8s*>(w0p + off);
      A1[i3][kc] = *reinterpret_cast<const v8s*>(w1p + off);
      A2[i3][kc] = *reinterpret_cast<const v8s*>(w2p + off);
    }
  }
  v8s L0[2], L1[2], L2[2];
#pragma unroll
  for (int kc = 0; kc < 2; ++kc) {
    const int off = (192 + s) * 64 + 32 * kc + 8 * hi;   // tile 12
    L0[kc] = *reinterpret_cast<const v8s*>(w0p + off);
    L1[kc] = *reinterpret_cast<const v8s*>(w1p + off);
    L2[kc] = *reinterpret_cast<const v8s*>(w2p + off);
  }

  const float bd0 = bd[0], bd1 = bd[1];
  const int u0i = 16 * w + 4 * hi;        // this wave's gate-unit group
  const float4 czv  = *reinterpret_cast<const float4*>(&c0zr[u0i]);
  const float4 crv  = *reinterpret_cast<const float4*>(&c0zr[64 + u0i]);
  const float4 bh0v = *reinterpret_cast<const float4*>(&bh0a[u0i]);
  const float4 bh1v = *reinterpret_cast<const float4*>(&bh1a[u0i]);
  const float4 wz0  = *reinterpret_cast<const float4*>(&cw0[u0i]);
  const float4 wz1  = *reinterpret_cast<const float4*>(&cw1[u0i]);
  const float4 wr0  = *reinterpret_cast<const float4*>(&cw0[64 + u0i]);
  const float4 wr1  = *reinterpret_cast<const float4*>(&cw1[64 + u0i]);
  const float4 wh0  = *reinterpret_cast<const float4*>(&cw0[128 + u0i]);
  const float4 wh1  = *reinterpret_cast<const float4*>(&cw1[128 + u0i]);

  const int kcw = w >> 1;
  const int hgw = (2 * w + (hi >> 1)) & 3;
  const int i0  = (hi & 1) * 4;

  float hreg[4] = {0.0f, 0.0f, 0.0f, 0.0f};
  float lp = 0.0f;
  int p = 0;

  for (int t = 0; t <= NSITES; ++t) {
    // ---- hoisted gumbel read (independent LDS op, hides under B-reads) --
    float2 gc = make_float2(0.0f, 0.0f);
    if (t > 0) gc = gl[(t - 1) * 16 + s];

    // ---- B fragments of h(t-1) from LDS ----
    const ushort* rb = bsp[p] + hi * 128 + s * 8;
    v8s B0[2], B1[2], B2[2];
#pragma unroll
    for (int kc = 0; kc < 2; ++kc) {
      B0[kc] = *reinterpret_cast<const v8s*>(rb + kc * 512);
      B1[kc] = *reinterpret_cast<const v8s*>(rb + 1024 + kc * 512);
      B2[kc] = *reinterpret_cast<const v8s*>(rb + 2048 + kc * 512);
    }

    // ---- logits tile (6 products, low -> high) ----
    v4f al = {0.0f, 0.0f, 0.0f, 0.0f};
#pragma unroll
    for (int kc = 0; kc < 2; ++kc) al = MF(L1[kc], B1[kc], al);
#pragma unroll
    for (int kc = 0; kc < 2; ++kc) al = MF(L2[kc], B0[kc], al);
#pragma unroll
    for (int kc = 0; kc < 2; ++kc) al = MF(L0[kc], B2[kc], al);
#pragma unroll
    for (int kc = 0; kc < 2; ++kc) al = MF(L1[kc], B0[kc], al);
#pragma unroll
    for (int kc = 0; kc < 2; ++kc) al = MF(L0[kc], B1[kc], al);
#pragma unroll
    for (int kc = 0; kc < 2; ++kc) al = MF(L0[kc], B0[kc], al);

    // ---- unit tiles (independent of decision; keep MFMA pipe fed) ----
    v4f acc[3];
    if (t < NSITES) {
#pragma unroll
      for (int i3 = 0; i3 < 3; ++i3) {
        v4f a = {0.0f, 0.0f, 0.0f, 0.0f};
#pragma unroll
        for (int kc = 0; kc < 2; ++kc) a = MF(A2[i3][kc], B0[kc], a);
#pragma unroll
        for (int kc = 0; kc < 2; ++kc) a = MF(A0[i3][kc], B2[kc], a);
#pragma unroll
        for (int kc = 0; kc < 2; ++kc) a = MF(A1[i3][kc], B1[kc], a);
#pragma unroll
        for (int kc = 0; kc < 2; ++kc) a = MF(A1[i3][kc], B0[kc], a);
#pragma unroll
        for (int kc = 0; kc < 2; ++kc) a = MF(A0[i3][kc], B1[kc], a);
#pragma unroll
        for (int kc = 0; kc < 2; ++kc) a = MF(A0[i3][kc], B0[kc], a);
        acc[i3] = a;
      }
    }

    // ---- EARLY decision compare: no exp/log on the gates' path ----
    int scd = 0;
    float l0 = 0.0f, l1 = 0.0f;
    if (t > 0) {
      l0 = al[0] + bd0;
      l1 = al[1] + bd1;
      scd = ((l1 + gc.y) > (l0 + gc.x)) ? 1 : 0;
    }

    if (t < NSITES) {
      // ---- gates for this wave's 16 units (identical math) ----
      float selz[4], selr[4], selh[4];
      if (t == 0) {
#pragma unroll
        for (int r = 0; r < 4; ++r) { selz[r] = 0.0f; selr[r] = 0.0f; selh[r] = 0.0f; }
      } else {
#pragma unroll
        for (int r = 0; r < 4; ++r) {
          selz[r] = scd ? F4(wz1, r) : F4(wz0, r);
          selr[r] = scd ? F4(wr1, r) : F4(wr0, r);
          selh[r] = scd ? F4(wh1, r) : F4(wh0, r);
        }
      }

      uint sp0[4], sp1[4], sp2[4];
#pragma unroll
      for (int r = 0; r < 4; ++r) {
        const float zin = acc[0][r] + F4(czv, r) + selz[r];
        const float rin = acc[1][r] + F4(crv, r) + selr[r];
        const float rhv = acc[2][r] + F4(bh1v, r);
        const float xhv = F4(bh0v, r) + selh[r];
        const float zg = sigmoid_xla(zin);
        const float rg = sigmoid_xla(rin);
        const float hg = tanhf(xhv + rg * rhv);
        const float hn = zg * hreg[r] + (1.0f - zg) * hg;
        hreg[r] = hn;
        const uint u0 = __float_as_uint(hn) & 0xffff0000u;
        const float f0 = __uint_as_float(u0);
        const float r1f = hn - f0;
        const uint u1 = __float_as_uint(r1f) & 0xffff0000u;
        const float f1 = __uint_as_float(u1);
        const float r2f = r1f - f1;
        const uint u2 = __float_as_uint(r2f) & 0xffff0000u;
        sp0[r] = u0 >> 16; sp1[r] = u1 >> 16; sp2[r] = u2 >> 16;
      }
      ushort* wb = bsp[p ^ 1] + kcw * 512 + hgw * 128 + s * 8 + i0;
      {
        uint2 q;
        q.x = sp0[0] | (sp0[1] << 16); q.y = sp0[2] | (sp0[3] << 16);
        *reinterpret_cast<uint2*>(wb) = q;
        q.x = sp1[0] | (sp1[1] << 16); q.y = sp1[2] | (sp1[3] << 16);
        *reinterpret_cast<uint2*>(wb + 1024) = q;
        q.x = sp2[0] | (sp2[1] << 16); q.y = sp2[2] | (sp2[3] << 16);
        *reinterpret_cast<uint2*>(wb + 2048) = q;
      }
    }

    // ---- DEFERRED scoring: exp/log chain overlaps barrier + next reads --
    if (t > 0) {
      const float mmax = fmaxf(l0, l1);
      const float sh0 = l0 - mmax, sh1 = l1 - mmax;
      const float lse = logf(expf(sh0) + expf(sh1));
      lp += (scd ? sh1 : sh0) - lse;
      if (tid < 16) out_s[(size_t)(base + s) * NSITES + (t - 1)] = (float)scd;
    }

    __syncthreads();   // h(t) splits visible; reads of bsp[p] complete
    p ^= 1;
  }

  if (tid < 16) out_lp[base + s] = 0.5f * lp;
}

// ---------------- fallback (ws too small): proven bit-exact path ----------
__global__ __launch_bounds__(64)
void rnn_plain(const float* __restrict__ Wi, const float* __restrict__ Wh,
               const float* __restrict__ bb, const float* __restrict__ Wd,
               const float* __restrict__ bd,
               float* __restrict__ out_s, float* __restrict__ out_lp) {
  const int lane = threadIdx.x;
  const int b = blockIdx.x;

  float wz[NHID], wr[NHID], wh[NHID];
#pragma unroll
  for (int j = 0; j < NHID; ++j) {
    wz[j] = Wh[j * 192 + lane];
    wr[j] = Wh[j * 192 + 64 + lane];
    wh[j] = Wh[j * 192 + 128 + lane];
  }
  const float b1z = bb[192 + lane];
  const float b1r = bb[192 + 64 + lane];
  const float b1h = bb[192 + 128 + lane];
  const float m0z = bb[lane], m0r = bb[64 + lane], m0h = bb[128 + lane];
  const float m1z = Wi[lane] + m0z, m1r = Wi[64 + lane] + m0r, m1h = Wi[128 + lane] + m0h;
  const float m2z = Wi[192 + lane] + m0z, m2r = Wi[192 + 64 + lane] + m0r,
              m2h = Wi[192 + 128 + lane] + m0h;
  const float wd0 = Wd[lane * 2 + 0], wd1 = Wd[lane * 2 + 1];
  const float bd0 = bd[0], bd1 = bd[1];

  float h = 0.0f, lpsum = 0.0f;
  float xz = m0z, xr = m0r, xh = m0h;

  for (int t = 0; t < NSITES; ++t) {
    uint32_t kt0, kt1;
    tf2x32(0u, 1234u, 0u, (uint32_t)t, kt0, kt1);
    const float g0 = gumb_from_bits(rbits32(kt0, kt1, (uint32_t)(2 * b)));
    const float g1 = gumb_from_bits(rbits32(kt0, kt1, (uint32_t)(2 * b + 1)));

    float az = 0.0f, ar = 0.0f, ah = 0.0f;
#pragma unroll
    for (int j = 0; j < NHID; ++j) {
      const float hj = __int_as_float(__builtin_amdgcn_readlane(__float_as_int(h), j));
      az = fmaf(hj, wz[j], az);
      ar = fmaf(hj, wr[j], ar);
      ah = fmaf(hj, wh[j], ah);
    }
    const float rz = az + b1z, rr = ar + b1r, rh = ah + b1h;
    const float zg = sigmoid_xla(xz + rz);
    const float rg = sigmoid_xla(xr + rr);
    const float hg = tanhf(xh + rg * rh);
    h = zg * h + (1.0f - zg) * hg;

    float p0 = h * wd0, p1 = h * wd1;
#pragma unroll
    for (int off = 32; off > 0; off >>= 1) {
      p0 += __shfl_xor(p0, off, 64);
      p1 += __shfl_xor(p1, off, 64);
    }
    const float l0 = p0 + bd0, l1 = p1 + bd1;
    const float mmax = fmaxf(l0, l1);
    const float sh0 = l0 - mmax, sh1 = l1 - mmax;
    const float lse = logf(expf(sh0) + expf(sh1));
    const int si = ((l1 + g1) > (l0 + g0)) ? 1 : 0;
    lpsum += (si ? sh1 : sh0) - lse;
    if (lane == 0) out_s[(size_t)b * NSITES + t] = (float)si;
    xz = si ? m2z : m1z;
    xr = si ? m2r : m1r;
    xh = si ? m2h : m1h;
  }

  if (lane == 0) out_lp[b] = 0.5f * lpsum;
}

extern "C" void kernel_launch(void* const* d_in, const int* in_sizes, int n_in,
                              void* d_out, int out_size, void* d_ws, size_t ws_size,
                              hipStream_t stream) {
  const float* Wi = (const float*)d_in[1];
  const float* Wh = (const float*)d_in[2];
  const float* bb = (const float*)d_in[3];
  const float* Wd = (const float*)d_in[4];
  const float* bd = (const float*)d_in[5];

  float* out    = (float*)d_out;
  float* out_s  = out;                           // [8192][256]
  float* out_lp = out + (size_t)BATCH * NSITES;  // [8192]

  const size_t wb = (size_t)208 * 64 * sizeof(ushort);   // 26 KiB per split

  if (ws_size >= 3 * wb) {
    ushort* w0 = (ushort*)d_ws;
    ushort* w1 = w0 + 208 * 64;
    ushort* w2 = w1 + 208 * 64;
    split_awt<<<(208 * 64 + 255) / 256, 256, 0, stream>>>(Wh, Wd, w0, w1, w2);
    rnn_mfma10<<<BATCH / 16, 256, 0, stream>>>(Wi, bb, bd, w0, w1, w2, out_s, out_lp);
  } else {
    rnn_plain<<<BATCH, 64, 0, stream>>>(Wi, Wh, bb, Wd, bd, out_s, out_lp);
  }
}